// Round 10
// baseline (287.012 us; speedup 1.0000x reference)
//
#include <hip/hip_runtime.h>
#include <math.h>

namespace {

constexpr int Bn = 8;
constexpr int Sn = 1024;
constexpr int Dn = 256;
constexpr int Mn = Bn * Sn;    // 8192 rows
constexpr int L  = 32;         // chunk length
constexpr int NSEG = Sn / L;   // 32 chunks

__device__ float g_den[Bn * Sn];   // raw n·q per (b,t); clamp applied in out_gemm

__device__ __forceinline__ float sigmoidf_(float x) {
    return 1.0f / (1.0f + __expf(-x));
}

// 16-value split butterfly over 64 lanes (HW-validated in r7).
__device__ __forceinline__ void multi_reduce16(float v[16], int lane) {
    {   const bool hi = (lane & 32) != 0;
        #pragma unroll
        for (int i = 0; i < 8; ++i) {
            const float send = hi ? v[i] : v[i + 8];
            const float recv = __shfl_xor(send, 32, 64);
            v[i] = (hi ? v[i + 8] : v[i]) + recv;
        } }
    {   const bool hi = (lane & 16) != 0;
        #pragma unroll
        for (int i = 0; i < 4; ++i) {
            const float send = hi ? v[i] : v[i + 4];
            const float recv = __shfl_xor(send, 16, 64);
            v[i] = (hi ? v[i + 4] : v[i]) + recv;
        } }
    {   const bool hi = (lane & 8) != 0;
        #pragma unroll
        for (int i = 0; i < 2; ++i) {
            const float send = hi ? v[i] : v[i + 2];
            const float recv = __shfl_xor(send, 8, 64);
            v[i] = (hi ? v[i + 2] : v[i]) + recv;
        } }
    {   const bool hi = (lane & 4) != 0;
        const float send = hi ? v[0] : v[1];
        const float recv = __shfl_xor(send, 4, 64);
        v[0] = (hi ? v[1] : v[0]) + recv;
    }
    v[0] += __shfl_xor(v[0], 2, 64);
    v[0] += __shfl_xor(v[0], 1, 64);
}

// ---------------------------------------------------------------------------
// Fused projection GEMM as ONE logical GEMM: M=8192, N=1024 (4 stacked W's),
// K=256. 128x128 tile, microtile = 2x2 blocks of 4x4 (halves 64 apart) so
// every LDS read is <=2-way bank aliased (free). Each 128-col n-tile maps
// wholly to one weight matrix / activation / output.
// ---------------------------------------------------------------------------
__global__ __launch_bounds__(256) void proj_gemm(
    const float* __restrict__ X,
    const float* __restrict__ W0, const float* __restrict__ b0,
    const float* __restrict__ W1, const float* __restrict__ b1,
    const float* __restrict__ W2, const float* __restrict__ b2,
    const float* __restrict__ W3, const float* __restrict__ b3,
    float* __restrict__ Y0, float* __restrict__ Y1,
    float* __restrict__ Y2, float* __restrict__ Y3)
{
    __shared__ float As[16][132];   // [k][m] 128 + pad
    __shared__ float Bs[16][132];   // [k][n]

    const int tid = threadIdx.x;
    const int mb  = blockIdx.x * 128;
    const int nbg = blockIdx.y * 128;      // global n in 0..1023
    const int widx = nbg >> 8;             // which W / activation
    const int ro   = nbg & 255;            // row offset inside that W (0 or 128)

    const float* Wsel = (widx == 0) ? W0 : (widx == 1) ? W1 : (widx == 2) ? W2 : W3;
    const float* bsel = (widx == 0) ? b0 : (widx == 1) ? b1 : (widx == 2) ? b2 : b3;
    float*       Ysel = (widx == 0) ? Y0 : (widx == 1) ? Y1 : (widx == 2) ? Y2 : Y3;

    const int lr = tid >> 2;          // 0..63 load row
    const int lk = (tid & 3) * 4;     // 0,4,8,12
    const int tx = tid & 15;
    const int ty = tid >> 4;

    float acc[2][2][4][4];
    #pragma unroll
    for (int hm = 0; hm < 2; ++hm)
        #pragma unroll
        for (int hn = 0; hn < 2; ++hn)
            #pragma unroll
            for (int i = 0; i < 4; ++i)
                #pragma unroll
                for (int j = 0; j < 4; ++j) acc[hm][hn][i][j] = 0.0f;

    for (int k0 = 0; k0 < Dn; k0 += 16) {
        const float4 a0 = *(const float4*)(X + (size_t)(mb + lr) * Dn + k0 + lk);
        const float4 a1 = *(const float4*)(X + (size_t)(mb + 64 + lr) * Dn + k0 + lk);
        const float4 w0 = *(const float4*)(Wsel + (size_t)(ro + lr) * Dn + k0 + lk);
        const float4 w1 = *(const float4*)(Wsel + (size_t)(ro + 64 + lr) * Dn + k0 + lk);
        __syncthreads();
        As[lk+0][lr] = a0.x; As[lk+1][lr] = a0.y; As[lk+2][lr] = a0.z; As[lk+3][lr] = a0.w;
        As[lk+0][64+lr] = a1.x; As[lk+1][64+lr] = a1.y; As[lk+2][64+lr] = a1.z; As[lk+3][64+lr] = a1.w;
        Bs[lk+0][lr] = w0.x; Bs[lk+1][lr] = w0.y; Bs[lk+2][lr] = w0.z; Bs[lk+3][lr] = w0.w;
        Bs[lk+0][64+lr] = w1.x; Bs[lk+1][64+lr] = w1.y; Bs[lk+2][64+lr] = w1.z; Bs[lk+3][64+lr] = w1.w;
        __syncthreads();

        #pragma unroll
        for (int kk = 0; kk < 16; ++kk) {
            const float4 alo = *(const float4*)&As[kk][ty * 4];
            const float4 ahi = *(const float4*)&As[kk][64 + ty * 4];
            const float4 blo = *(const float4*)&Bs[kk][tx * 4];
            const float4 bhi = *(const float4*)&Bs[kk][64 + tx * 4];
            const float am[2][4] = {{alo.x, alo.y, alo.z, alo.w},
                                    {ahi.x, ahi.y, ahi.z, ahi.w}};
            const float bn[2][4] = {{blo.x, blo.y, blo.z, blo.w},
                                    {bhi.x, bhi.y, bhi.z, bhi.w}};
            #pragma unroll
            for (int hm = 0; hm < 2; ++hm)
                #pragma unroll
                for (int hn = 0; hn < 2; ++hn)
                    #pragma unroll
                    for (int i = 0; i < 4; ++i)
                        #pragma unroll
                        for (int j = 0; j < 4; ++j)
                            acc[hm][hn][i][j] = fmaf(am[hm][i], bn[hn][j], acc[hm][hn][i][j]);
        }
    }

    #pragma unroll
    for (int hn = 0; hn < 2; ++hn) {
        const int coln = ro + hn * 64 + tx * 4;
        const float4 bv = *(const float4*)(bsel + coln);
        #pragma unroll
        for (int hm = 0; hm < 2; ++hm)
            #pragma unroll
            for (int i = 0; i < 4; ++i) {
                const int row = mb + hm * 64 + ty * 4 + i;
                float4 o;
                o.x = acc[hm][hn][i][0] + bv.x;
                o.y = acc[hm][hn][i][1] + bv.y;
                o.z = acc[hm][hn][i][2] + bv.z;
                o.w = acc[hm][hn][i][3] + bv.w;
                if (widx == 2) {
                    o.x = sigmoidf_(o.x); o.y = sigmoidf_(o.y);
                    o.z = sigmoidf_(o.z); o.w = sigmoidf_(o.w);
                } else if (widx == 3) {
                    o.x = __expf(o.x); o.y = __expf(o.y);
                    o.z = __expf(o.z); o.w = __expf(o.w);
                }
                *(float4*)(Ysel + (size_t)row * Dn + coln) = o;
            }
    }
}

// ---------------------------------------------------------------------------
// Output GEMM: out = (num * invden) @ Wo^T + bo. 128x64 tile, microtile
// 2x(4)x4 with row halves 64 apart (conflict-free reads). Grid (64,4).
// ---------------------------------------------------------------------------
__global__ __launch_bounds__(256) void out_gemm(
    const float* __restrict__ X, const float* __restrict__ W,
    const float* __restrict__ bias, float* __restrict__ Y)
{
    __shared__ float As[16][132];
    __shared__ float Bs[16][68];

    const int tid = threadIdx.x;
    const int mb  = blockIdx.x * 128;
    const int nb  = blockIdx.y * 64;
    const int lr  = tid >> 2;
    const int lk  = (tid & 3) * 4;
    const int tx  = tid & 15;
    const int ty  = tid >> 4;

    const float dn0 = g_den[mb + lr];
    const float dn1 = g_den[mb + 64 + lr];
    const float invd0 = 1.0f / fmaxf(fabsf(dn0), 1.0f);
    const float invd1 = 1.0f / fmaxf(fabsf(dn1), 1.0f);

    float acc[2][4][4];
    #pragma unroll
    for (int hm = 0; hm < 2; ++hm)
        #pragma unroll
        for (int i = 0; i < 4; ++i)
            #pragma unroll
            for (int j = 0; j < 4; ++j) acc[hm][i][j] = 0.0f;

    for (int k0 = 0; k0 < Dn; k0 += 16) {
        float4 a0 = *(const float4*)(X + (size_t)(mb + lr) * Dn + k0 + lk);
        float4 a1 = *(const float4*)(X + (size_t)(mb + 64 + lr) * Dn + k0 + lk);
        const float4 w = *(const float4*)(W + (size_t)(nb + lr) * Dn + k0 + lk);
        a0.x *= invd0; a0.y *= invd0; a0.z *= invd0; a0.w *= invd0;
        a1.x *= invd1; a1.y *= invd1; a1.z *= invd1; a1.w *= invd1;
        __syncthreads();
        As[lk+0][lr] = a0.x; As[lk+1][lr] = a0.y; As[lk+2][lr] = a0.z; As[lk+3][lr] = a0.w;
        As[lk+0][64+lr] = a1.x; As[lk+1][64+lr] = a1.y; As[lk+2][64+lr] = a1.z; As[lk+3][64+lr] = a1.w;
        Bs[lk+0][lr] = w.x; Bs[lk+1][lr] = w.y; Bs[lk+2][lr] = w.z; Bs[lk+3][lr] = w.w;
        __syncthreads();

        #pragma unroll
        for (int kk = 0; kk < 16; ++kk) {
            const float4 alo = *(const float4*)&As[kk][ty * 4];
            const float4 ahi = *(const float4*)&As[kk][64 + ty * 4];
            const float4 bv  = *(const float4*)&Bs[kk][tx * 4];
            const float am[2][4] = {{alo.x, alo.y, alo.z, alo.w},
                                    {ahi.x, ahi.y, ahi.z, ahi.w}};
            const float bb[4] = {bv.x, bv.y, bv.z, bv.w};
            #pragma unroll
            for (int hm = 0; hm < 2; ++hm)
                #pragma unroll
                for (int i = 0; i < 4; ++i)
                    #pragma unroll
                    for (int j = 0; j < 4; ++j)
                        acc[hm][i][j] = fmaf(am[hm][i], bb[j], acc[hm][i][j]);
        }
    }

    const float4 bbv = *(const float4*)(bias + nb + tx * 4);
    #pragma unroll
    for (int hm = 0; hm < 2; ++hm)
        #pragma unroll
        for (int i = 0; i < 4; ++i) {
            const size_t rowoff = (size_t)(mb + hm * 64 + ty * 4 + i) * Dn + nb + tx * 4;
            float4 o;
            o.x = acc[hm][i][0] + bbv.x; o.y = acc[hm][i][1] + bbv.y;
            o.z = acc[hm][i][2] + bbv.z; o.w = acc[hm][i][3] + bbv.w;
            *(float4*)(Y + rowoff) = o;
        }
}

// ---------------------------------------------------------------------------
// gate_prep: per (chunk m, batch b), thread = r. Elementwise chunk scans:
//   G[τ,r] = Π_{u<=τ} f ;  Ṽ[τ,r] = i·v/G ;  Ñ[τ,r] = Σ i·k/G
// ---------------------------------------------------------------------------
__global__ __launch_bounds__(256) void gate_prep(
    const float* __restrict__ Pf, const float* __restrict__ Pi,
    const float* __restrict__ Pk, const float* __restrict__ Pq,
    float* __restrict__ Gc, float* __restrict__ Vt, float* __restrict__ Nt,
    float* __restrict__ Aend, float* __restrict__ un)
{
    const int m = blockIdx.x;
    const int b = blockIdx.y;
    const int r = threadIdx.x;
    const size_t base = (size_t)b * Sn * Dn + (size_t)m * L * Dn + r;

    float G = 1.0f, Nacc = 0.0f;
    #pragma unroll 4
    for (int t = 0; t < L; ++t) {
        const size_t off = base + (size_t)t * Dn;
        const float f  = Pf[off];
        const float iv = Pi[off];
        const float kv = Pk[off];
        const float vv = Pq[off];     // v = q projection (Wv unused)
        G *= f;
        const float rG = 1.0f / G;
        Gc[off] = G;
        Vt[off] = iv * vv * rG;
        Nacc = fmaf(iv * kv, rG, Nacc);
        Nt[off] = Nacc;
    }
    const size_t s = ((size_t)b * NSEG + m) * Dn + r;
    Aend[s] = G;
    un[s]   = G * Nacc;
}

// ---------------------------------------------------------------------------
// ut_gemm: UT[b,m][c,r] = Aend[r] * Σ_σ K[σ,c]·Ṽ[σ,r]
// ---------------------------------------------------------------------------
__global__ __launch_bounds__(256) void ut_gemm(
    const float* __restrict__ Pk, const float* __restrict__ Vt,
    const float* __restrict__ Aend, float* __restrict__ UT)
{
    __shared__ float As[L][68];   // K^T tile: As[σ][c]
    __shared__ float Bs[L][68];   // Ṽ tile:  Bs[σ][r]

    const int bm   = blockIdx.x;           // b*NSEG + m
    const int tile = blockIdx.y;
    const int cb   = (tile >> 2) * 64;
    const int rb   = (tile & 3) * 64;
    const int b    = bm >> 5;
    const int m    = bm & 31;
    const size_t kb = (size_t)b * Sn * Dn + (size_t)m * L * Dn;
    const int tid = threadIdx.x;

    #pragma unroll
    for (int n = 0; n < 8; ++n) {
        const int e  = n * 256 + tid;
        const int sg = e >> 6;
        const int cc = e & 63;
        As[sg][cc] = Pk[kb + (size_t)sg * Dn + cb + cc];
        Bs[sg][cc] = Vt[kb + (size_t)sg * Dn + rb + cc];
    }
    __syncthreads();

    const int tx = tid & 15;
    const int ty = tid >> 4;
    float acc[4][4];
    #pragma unroll
    for (int i = 0; i < 4; ++i)
        #pragma unroll
        for (int j = 0; j < 4; ++j) acc[i][j] = 0.0f;

    #pragma unroll
    for (int sg = 0; sg < L; ++sg) {
        const float4 a4 = *(const float4*)&As[sg][ty * 4];
        const float4 b4 = *(const float4*)&Bs[sg][tx * 4];
        const float aa[4] = {a4.x, a4.y, a4.z, a4.w};
        const float bb[4] = {b4.x, b4.y, b4.z, b4.w};
        #pragma unroll
        for (int i = 0; i < 4; ++i)
            #pragma unroll
            for (int j = 0; j < 4; ++j)
                acc[i][j] = fmaf(aa[i], bb[j], acc[i][j]);
    }

    const float4 g4 = *(const float4*)(Aend + (size_t)bm * Dn + rb + tx * 4);
    float* ub = UT + (size_t)bm * Dn * Dn;
    #pragma unroll
    for (int i = 0; i < 4; ++i) {
        float4 o;
        o.x = acc[i][0] * g4.x; o.y = acc[i][1] * g4.y;
        o.z = acc[i][2] * g4.z; o.w = acc[i][3] * g4.w;
        *(float4*)(ub + (size_t)(cb + ty * 4 + i) * Dn + rb + tx * 4) = o;
    }
}

// ---------------------------------------------------------------------------
// compose: sequential over chunks (32 steps, elementwise).
// ---------------------------------------------------------------------------
__global__ __launch_bounds__(256) void compose(
    const float* __restrict__ UT, const float* __restrict__ Aend,
    const float* __restrict__ un,
    float* __restrict__ CinT, float* __restrict__ nin)
{
    const int gx = blockIdx.x;
    const int b  = blockIdx.y;
    const int tid = threadIdx.x;

    if (gx == 64) {
        const int r = tid;
        float acc = 0.0f;
        for (int m = 0; m < NSEG; ++m) {
            const size_t s = ((size_t)b * NSEG + m) * Dn + r;
            nin[s] = acc;
            acc = fmaf(Aend[s], acc, un[s]);
        }
        return;
    }

    const int id = gx * 256 + tid;       // 0..16383
    const int c  = id >> 6;
    const int r4 = (id & 63) * 4;

    float4 acc = make_float4(0.f, 0.f, 0.f, 0.f);
    for (int m = 0; m < NSEG; ++m) {
        const size_t bm  = (size_t)b * NSEG + m;
        const size_t idx = bm * Dn * Dn + (size_t)c * Dn + r4;
        *(float4*)(CinT + idx) = acc;
        const float4 a4 = *(const float4*)(Aend + bm * Dn + r4);
        const float4 u4 = *(const float4*)(UT + idx);
        acc.x = fmaf(a4.x, acc.x, u4.x);
        acc.y = fmaf(a4.y, acc.y, u4.y);
        acc.z = fmaf(a4.z, acc.z, u4.z);
        acc.w = fmaf(a4.w, acc.w, u4.w);
    }
}

// ---------------------------------------------------------------------------
// s_gemm: S[b,m][τ,σ] = k_σ·q_τ for σ<=τ else 0.
// ---------------------------------------------------------------------------
__global__ __launch_bounds__(256) void s_gemm(
    const float* __restrict__ Pk, const float* __restrict__ Pq,
    float* __restrict__ Ssm)
{
    const int m = blockIdx.x;
    const int b = blockIdx.y;
    const size_t qb = (size_t)b * Sn * Dn + (size_t)m * L * Dn;
    const int tid = threadIdx.x;
    const int tau = tid >> 3;
    const int s4  = (tid & 7) * 4;

    float a0 = 0.f, a1 = 0.f, a2 = 0.f, a3 = 0.f;
    #pragma unroll 4
    for (int c = 0; c < Dn; c += 4) {
        const float4 q4 = *(const float4*)(Pq + qb + (size_t)tau * Dn + c);
        const float4 k0 = *(const float4*)(Pk + qb + (size_t)(s4 + 0) * Dn + c);
        const float4 k1 = *(const float4*)(Pk + qb + (size_t)(s4 + 1) * Dn + c);
        const float4 k2 = *(const float4*)(Pk + qb + (size_t)(s4 + 2) * Dn + c);
        const float4 k3 = *(const float4*)(Pk + qb + (size_t)(s4 + 3) * Dn + c);
        a0 += q4.x*k0.x + q4.y*k0.y + q4.z*k0.z + q4.w*k0.w;
        a1 += q4.x*k1.x + q4.y*k1.y + q4.z*k1.z + q4.w*k1.w;
        a2 += q4.x*k2.x + q4.y*k2.y + q4.z*k2.z + q4.w*k2.w;
        a3 += q4.x*k3.x + q4.y*k3.y + q4.z*k3.z + q4.w*k3.w;
    }
    float* out = Ssm + ((size_t)b * NSEG + m) * L * L + (size_t)tau * L + s4;
    out[0] = (s4 + 0 <= tau) ? a0 : 0.0f;
    out[1] = (s4 + 1 <= tau) ? a1 : 0.0f;
    out[2] = (s4 + 2 <= tau) ? a2 : 0.0f;
    out[3] = (s4 + 3 <= tau) ? a3 : 0.0f;
}

// ---------------------------------------------------------------------------
// num_gemm: Pnum[τ,r] = G[τ,r]·( Σ_σ S[τ,σ]Ṽ[σ,r] + Σ_c Q[τ,c]CinT[c,r] )
// ---------------------------------------------------------------------------
__global__ __launch_bounds__(256) void num_gemm(
    const float* __restrict__ Pq, const float* __restrict__ Vt,
    const float* __restrict__ Gc, const float* __restrict__ Ssm,
    const float* __restrict__ CinT, float* __restrict__ Pnum)
{
    __shared__ float Sld[L][33];
    __shared__ float Qld[L][257];

    const int rb = blockIdx.x * 128;
    const int m  = blockIdx.y;
    const int b  = blockIdx.z;
    const size_t qb = (size_t)b * Sn * Dn + (size_t)m * L * Dn;
    const size_t ub = ((size_t)b * NSEG + m) * Dn * Dn;
    const size_t sb = ((size_t)b * NSEG + m) * L * L;
    const int tid = threadIdx.x;

    #pragma unroll
    for (int n = 0; n < 4; ++n) {
        const int e = n * 256 + tid;
        Sld[e >> 5][e & 31] = Ssm[sb + e];
    }
    #pragma unroll
    for (int n = 0; n < L; ++n)
        Qld[n][tid] = Pq[qb + (size_t)n * Dn + tid];
    __syncthreads();

    const int tx = tid & 31;
    const int ty = tid >> 5;
    const int r4 = rb + tx * 4;
    const int t4 = ty * 4;

    float4 acc[4];
    #pragma unroll
    for (int i = 0; i < 4; ++i) acc[i] = make_float4(0.f, 0.f, 0.f, 0.f);

    // phase 1: S @ Ṽ  (K = 32)
    #pragma unroll 4
    for (int sg = 0; sg < L; ++sg) {
        const float4 v4 = *(const float4*)(Vt + qb + (size_t)sg * Dn + r4);
        #pragma unroll
        for (int i = 0; i < 4; ++i) {
            const float s = Sld[t4 + i][sg];
            acc[i].x = fmaf(s, v4.x, acc[i].x);
            acc[i].y = fmaf(s, v4.y, acc[i].y);
            acc[i].z = fmaf(s, v4.z, acc[i].z);
            acc[i].w = fmaf(s, v4.w, acc[i].w);
        }
    }

    // phase 2: Q @ Cin^T  (K = 256)
    #pragma unroll 8
    for (int c = 0; c < Dn; ++c) {
        const float4 ct = *(const float4*)(CinT + ub + (size_t)c * Dn + r4);
        #pragma unroll
        for (int i = 0; i < 4; ++i) {
            const float q = Qld[t4 + i][c];
            acc[i].x = fmaf(q, ct.x, acc[i].x);
            acc[i].y = fmaf(q, ct.y, acc[i].y);
            acc[i].z = fmaf(q, ct.z, acc[i].z);
            acc[i].w = fmaf(q, ct.w, acc[i].w);
        }
    }

    #pragma unroll
    for (int i = 0; i < 4; ++i) {
        const size_t off = qb + (size_t)(t4 + i) * Dn + r4;
        const float4 g4 = *(const float4*)(Gc + off);
        float4 o;
        o.x = acc[i].x * g4.x; o.y = acc[i].y * g4.y;
        o.z = acc[i].z * g4.z; o.w = acc[i].w * g4.w;
        *(float4*)(Pnum + off) = o;
    }
}

// ---------------------------------------------------------------------------
// den_kernel: g_den[b,t] = Σ_r q[t,r]·G[t,r]·(nin[m,r] + Ñ[t,r]),  m = t/L.
// ---------------------------------------------------------------------------
__global__ __launch_bounds__(256) void den_kernel(
    const float* __restrict__ Pq, const float* __restrict__ Gc,
    const float* __restrict__ Nt, const float* __restrict__ nin)
{
    const int gx = blockIdx.x;
    const int b  = blockIdx.y;
    const int tid  = threadIdx.x;
    const int lane = tid & 63;
    const int wv   = tid >> 6;
    const int c4   = lane * 4;

    for (int batch = 0; batch < 2; ++batch) {
        const int tbase = gx * 128 + wv * 32 + batch * 16;
        float p[16];
        #pragma unroll
        for (int j = 0; j < 16; ++j) {
            const int t = tbase + j;
            const int m = t >> 5;
            const size_t off = (size_t)b * Sn * Dn + (size_t)t * Dn + c4;
            const float4 q4 = *(const float4*)(Pq + off);
            const float4 g4 = *(const float4*)(Gc + off);
            const float4 n4 = *(const float4*)(Nt + off);
            const float4 i4 = *(const float4*)(nin + ((size_t)b * NSEG + m) * Dn + c4);
            p[j] = q4.x * g4.x * (i4.x + n4.x)
                 + q4.y * g4.y * (i4.y + n4.y)
                 + q4.z * g4.z * (i4.z + n4.z)
                 + q4.w * g4.w * (i4.w + n4.w);
        }
        multi_reduce16(p, lane);
        if ((lane & 3) == 0)
            g_den[b * Sn + tbase + ((lane >> 2) & 15)] = p[0];
    }
}

} // anonymous namespace

extern "C" void kernel_launch(void* const* d_in, const int* in_sizes, int n_in,
                              void* d_out, int out_size, void* d_ws, size_t ws_size,
                              hipStream_t stream)
{
    const float* x  = (const float*)d_in[0];
    const float* Wq = (const float*)d_in[1];  const float* bq = (const float*)d_in[2];
    const float* Wk = (const float*)d_in[3];  const float* bk = (const float*)d_in[4];
    // d_in[5]=Wv, d_in[6]=bv unused (reference uses W_q for v)
    const float* Wf = (const float*)d_in[7];  const float* bf = (const float*)d_in[8];
    const float* Wi = (const float*)d_in[9];  const float* bi = (const float*)d_in[10];
    const float* Wo = (const float*)d_in[11]; const float* bo = (const float*)d_in[12];
    float* out = (float*)d_out;

    float* ws = (float*)d_ws;
    const size_t sz = (size_t)Mn * Dn;            // 2,097,152 floats (8 MB)
    float* Pq = ws;
    float* Pk = ws + sz;
    float* Pf = ws + 2 * sz;
    float* Pi = ws + 3 * sz;
    float* Pn = ws + 4 * sz;                      // numerators
    float* Gc = ws + 5 * sz;                      // G cumprod  [b,t,r]
    float* Vt = ws + 6 * sz;                      // Ṽ          [b,t,r]
    float* Nt = ws + 7 * sz;                      // Ñ cumsum   [b,t,r]
    float* UT   = ws + 8 * sz;                    // [b,m][c][r]  8*sz
    float* CinT = ws + 16 * sz;                   // [b,m][c][r]  8*sz
    float* Ssm  = ws + 24 * sz;                   // [b,m][τ][σ]  262144
    float* Aend = Ssm + (size_t)Bn * NSEG * L * L;
    float* un   = Aend + (size_t)Bn * NSEG * Dn;
    float* nin  = un   + (size_t)Bn * NSEG * Dn;

    proj_gemm<<<dim3(Mn / 128, 1024 / 128), 256, 0, stream>>>(
        x, Wq, bq, Wk, bk, Wf, bf, Wi, bi, Pq, Pk, Pf, Pi);

    gate_prep<<<dim3(NSEG, Bn), 256, 0, stream>>>(
        Pf, Pi, Pk, Pq, Gc, Vt, Nt, Aend, un);

    ut_gemm<<<dim3(Bn * NSEG, 16), 256, 0, stream>>>(Pk, Vt, Aend, UT);

    compose<<<dim3(65, Bn), 256, 0, stream>>>(UT, Aend, un, CinT, nin);

    s_gemm<<<dim3(NSEG, Bn), 256, 0, stream>>>(Pk, Pq, Ssm);

    num_gemm<<<dim3(2, NSEG, Bn), 256, 0, stream>>>(
        Pq, Vt, Gc, Ssm, CinT, Pn);

    den_kernel<<<dim3(8, Bn), 256, 0, stream>>>(Pq, Gc, Nt, nin);

    out_gemm<<<dim3(Mn / 128, Dn / 64), 256, 0, stream>>>(Pn, Wo, bo, out);
}

// Round 11
// 257.482 us; speedup vs baseline: 1.1147x; 1.1147x over previous
//
#include <hip/hip_runtime.h>
#include <math.h>

namespace {

constexpr int Bn = 8;
constexpr int Sn = 1024;
constexpr int Dn = 256;
constexpr int Mn = Bn * Sn;    // 8192 rows
constexpr int L  = 32;         // chunk length
constexpr int NSEG = Sn / L;   // 32 chunks

typedef __attribute__((ext_vector_type(8))) short short8;   // 8 bf16 (4 VGPRs)
typedef __attribute__((ext_vector_type(4))) float f32x4;    // MFMA acc

__device__ float g_den[Bn * Sn];   // raw n·q per (b,t); clamp applied in out_gemm

__device__ __forceinline__ float sigmoidf_(float x) {
    return 1.0f / (1.0f + __expf(-x));
}

__device__ __forceinline__ unsigned short f2bf(float x) {
    unsigned int u = __float_as_uint(x);
    return (unsigned short)((u + 0x7FFF + ((u >> 16) & 1)) >> 16);   // RNE
}
__device__ __forceinline__ float bf2f(unsigned short h) {
    return __uint_as_float(((unsigned int)h) << 16);
}

// 16-value split butterfly over 64 lanes (HW-validated in r7).
__device__ __forceinline__ void multi_reduce16(float v[16], int lane) {
    {   const bool hi = (lane & 32) != 0;
        #pragma unroll
        for (int i = 0; i < 8; ++i) {
            const float send = hi ? v[i] : v[i + 8];
            const float recv = __shfl_xor(send, 32, 64);
            v[i] = (hi ? v[i + 8] : v[i]) + recv;
        } }
    {   const bool hi = (lane & 16) != 0;
        #pragma unroll
        for (int i = 0; i < 4; ++i) {
            const float send = hi ? v[i] : v[i + 4];
            const float recv = __shfl_xor(send, 16, 64);
            v[i] = (hi ? v[i + 4] : v[i]) + recv;
        } }
    {   const bool hi = (lane & 8) != 0;
        #pragma unroll
        for (int i = 0; i < 2; ++i) {
            const float send = hi ? v[i] : v[i + 2];
            const float recv = __shfl_xor(send, 8, 64);
            v[i] = (hi ? v[i + 2] : v[i]) + recv;
        } }
    {   const bool hi = (lane & 4) != 0;
        const float send = hi ? v[0] : v[1];
        const float recv = __shfl_xor(send, 4, 64);
        v[0] = (hi ? v[1] : v[0]) + recv;
    }
    v[0] += __shfl_xor(v[0], 2, 64);
    v[0] += __shfl_xor(v[0], 1, 64);
}

// ---------------------------------------------------------------------------
// MFMA bf16x3 fused projection GEMM. One logical GEMM M=8192, N=1024
// (4 stacked W's; each 128-col n-tile maps to one W / activation / output).
// 128x128 tile, BK=32; inputs split hi/lo bf16 in LDS; per 16x16 tile:
// acc += Ah*Bh + Ah*Bl + Al*Bh  (error ~2^-17, fp32-equivalent).
// ---------------------------------------------------------------------------
__global__ __launch_bounds__(256) void proj_gemm(
    const float* __restrict__ X,
    const float* __restrict__ W0, const float* __restrict__ b0,
    const float* __restrict__ W1, const float* __restrict__ b1,
    const float* __restrict__ W2, const float* __restrict__ b2,
    const float* __restrict__ W3, const float* __restrict__ b3,
    float* __restrict__ Y0, float* __restrict__ Y1,
    float* __restrict__ Y2, float* __restrict__ Y3)
{
    __shared__ unsigned short Ah[128][40];   // 32 k + 8 pad -> 80 B rows (16B aligned)
    __shared__ unsigned short Al[128][40];
    __shared__ unsigned short Bh[128][40];
    __shared__ unsigned short Bl[128][40];   // 4 x 10240 B = 40 KB

    const int tid = threadIdx.x;
    const int mb  = blockIdx.x * 128;
    const int nbg = blockIdx.y;            // 0..7
    const int widx = nbg >> 1;             // which W / activation
    const int ro   = (nbg & 1) * 128;      // row offset inside that W

    const float* Wsel = (widx == 0) ? W0 : (widx == 1) ? W1 : (widx == 2) ? W2 : W3;
    const float* bsel = (widx == 0) ? b0 : (widx == 1) ? b1 : (widx == 2) ? b2 : b3;
    float*       Ysel = (widx == 0) ? Y0 : (widx == 1) ? Y1 : (widx == 2) ? Y2 : Y3;

    const int lane = tid & 63;
    const int wv   = tid >> 6;
    const int wm   = (wv >> 1) * 64;       // wave quadrant
    const int wn   = (wv & 1) * 64;
    const int quad = lane >> 4;
    const int l16  = lane & 15;
    const int srow = tid >> 1;             // staging row 0..127
    const int skq  = (tid & 1) * 16;       // staging k offset 0/16

    f32x4 acc[4][4];
    #pragma unroll
    for (int mt = 0; mt < 4; ++mt)
        #pragma unroll
        for (int nt = 0; nt < 4; ++nt)
            acc[mt][nt] = (f32x4){0.f, 0.f, 0.f, 0.f};

    for (int k0 = 0; k0 < Dn; k0 += 32) {
        // ---- global loads (issued before barrier; fp32) ----
        float4 xa[4], wb[4];
        #pragma unroll
        for (int c = 0; c < 4; ++c) {
            xa[c] = *(const float4*)(X    + (size_t)(mb + srow) * Dn + k0 + skq + 4 * c);
            wb[c] = *(const float4*)(Wsel + (size_t)(ro + srow) * Dn + k0 + skq + 4 * c);
        }
        __syncthreads();
        // ---- split hi/lo and store to LDS ----
        #pragma unroll
        for (int c = 0; c < 4; ++c) {
            const float xs[4] = {xa[c].x, xa[c].y, xa[c].z, xa[c].w};
            const float wsv[4] = {wb[c].x, wb[c].y, wb[c].z, wb[c].w};
            ushort4 h, l;
            unsigned short t0;
            t0 = f2bf(xs[0]); h.x = t0; l.x = f2bf(xs[0] - bf2f(t0));
            t0 = f2bf(xs[1]); h.y = t0; l.y = f2bf(xs[1] - bf2f(t0));
            t0 = f2bf(xs[2]); h.z = t0; l.z = f2bf(xs[2] - bf2f(t0));
            t0 = f2bf(xs[3]); h.w = t0; l.w = f2bf(xs[3] - bf2f(t0));
            *(ushort4*)&Ah[srow][skq + 4 * c] = h;
            *(ushort4*)&Al[srow][skq + 4 * c] = l;
            t0 = f2bf(wsv[0]); h.x = t0; l.x = f2bf(wsv[0] - bf2f(t0));
            t0 = f2bf(wsv[1]); h.y = t0; l.y = f2bf(wsv[1] - bf2f(t0));
            t0 = f2bf(wsv[2]); h.z = t0; l.z = f2bf(wsv[2] - bf2f(t0));
            t0 = f2bf(wsv[3]); h.w = t0; l.w = f2bf(wsv[3] - bf2f(t0));
            *(ushort4*)&Bh[srow][skq + 4 * c] = h;
            *(ushort4*)&Bl[srow][skq + 4 * c] = l;
        }
        __syncthreads();

        // ---- fragment loads + MFMA ----
        short8 afh[4], afl[4];
        #pragma unroll
        for (int mt = 0; mt < 4; ++mt) {
            const int row = wm + mt * 16 + l16;
            afh[mt] = *(const short8*)&Ah[row][quad * 8];
            afl[mt] = *(const short8*)&Al[row][quad * 8];
        }
        #pragma unroll
        for (int nt = 0; nt < 4; ++nt) {
            const int row = wn + nt * 16 + l16;
            const short8 bfh = *(const short8*)&Bh[row][quad * 8];
            const short8 bfl = *(const short8*)&Bl[row][quad * 8];
            #pragma unroll
            for (int mt = 0; mt < 4; ++mt) {
                acc[mt][nt] = __builtin_amdgcn_mfma_f32_16x16x32_bf16(
                    afh[mt], bfh, acc[mt][nt], 0, 0, 0);
                acc[mt][nt] = __builtin_amdgcn_mfma_f32_16x16x32_bf16(
                    afh[mt], bfl, acc[mt][nt], 0, 0, 0);
                acc[mt][nt] = __builtin_amdgcn_mfma_f32_16x16x32_bf16(
                    afl[mt], bfh, acc[mt][nt], 0, 0, 0);
            }
        }
    }

    // ---- epilogue: D[row=(quad*4+reg)][col=l16] per 16x16 tile ----
    #pragma unroll
    for (int nt = 0; nt < 4; ++nt) {
        const int col = ro + wn + nt * 16 + l16;
        const float bv = bsel[col];
        #pragma unroll
        for (int mt = 0; mt < 4; ++mt) {
            const int rowb = mb + wm + mt * 16 + quad * 4;
            #pragma unroll
            for (int r = 0; r < 4; ++r) {
                float v = acc[mt][nt][r] + bv;
                if (widx == 2)      v = sigmoidf_(v);
                else if (widx == 3) v = __expf(v);
                Ysel[(size_t)(rowb + r) * Dn + col] = v;
            }
        }
    }
}

// ---------------------------------------------------------------------------
// Output GEMM: out = (num * invden) @ Wo^T + bo. 128x64 tile fp32 (r10).
// ---------------------------------------------------------------------------
__global__ __launch_bounds__(256) void out_gemm(
    const float* __restrict__ X, const float* __restrict__ W,
    const float* __restrict__ bias, float* __restrict__ Y)
{
    __shared__ float As[16][132];
    __shared__ float Bs[16][68];

    const int tid = threadIdx.x;
    const int mb  = blockIdx.x * 128;
    const int nb  = blockIdx.y * 64;
    const int lr  = tid >> 2;
    const int lk  = (tid & 3) * 4;
    const int tx  = tid & 15;
    const int ty  = tid >> 4;

    const float dn0 = g_den[mb + lr];
    const float dn1 = g_den[mb + 64 + lr];
    const float invd0 = 1.0f / fmaxf(fabsf(dn0), 1.0f);
    const float invd1 = 1.0f / fmaxf(fabsf(dn1), 1.0f);

    float acc[2][4][4];
    #pragma unroll
    for (int hm = 0; hm < 2; ++hm)
        #pragma unroll
        for (int i = 0; i < 4; ++i)
            #pragma unroll
            for (int j = 0; j < 4; ++j) acc[hm][i][j] = 0.0f;

    for (int k0 = 0; k0 < Dn; k0 += 16) {
        float4 a0 = *(const float4*)(X + (size_t)(mb + lr) * Dn + k0 + lk);
        float4 a1 = *(const float4*)(X + (size_t)(mb + 64 + lr) * Dn + k0 + lk);
        const float4 w = *(const float4*)(W + (size_t)(nb + lr) * Dn + k0 + lk);
        a0.x *= invd0; a0.y *= invd0; a0.z *= invd0; a0.w *= invd0;
        a1.x *= invd1; a1.y *= invd1; a1.z *= invd1; a1.w *= invd1;
        __syncthreads();
        As[lk+0][lr] = a0.x; As[lk+1][lr] = a0.y; As[lk+2][lr] = a0.z; As[lk+3][lr] = a0.w;
        As[lk+0][64+lr] = a1.x; As[lk+1][64+lr] = a1.y; As[lk+2][64+lr] = a1.z; As[lk+3][64+lr] = a1.w;
        Bs[lk+0][lr] = w.x; Bs[lk+1][lr] = w.y; Bs[lk+2][lr] = w.z; Bs[lk+3][lr] = w.w;
        __syncthreads();

        #pragma unroll
        for (int kk = 0; kk < 16; ++kk) {
            const float4 alo = *(const float4*)&As[kk][ty * 4];
            const float4 ahi = *(const float4*)&As[kk][64 + ty * 4];
            const float4 bv  = *(const float4*)&Bs[kk][tx * 4];
            const float am[2][4] = {{alo.x, alo.y, alo.z, alo.w},
                                    {ahi.x, ahi.y, ahi.z, ahi.w}};
            const float bb[4] = {bv.x, bv.y, bv.z, bv.w};
            #pragma unroll
            for (int hm = 0; hm < 2; ++hm)
                #pragma unroll
                for (int i = 0; i < 4; ++i)
                    #pragma unroll
                    for (int j = 0; j < 4; ++j)
                        acc[hm][i][j] = fmaf(am[hm][i], bb[j], acc[hm][i][j]);
        }
    }

    const float4 bbv = *(const float4*)(bias + nb + tx * 4);
    #pragma unroll
    for (int hm = 0; hm < 2; ++hm)
        #pragma unroll
        for (int i = 0; i < 4; ++i) {
            const size_t rowoff = (size_t)(mb + hm * 64 + ty * 4 + i) * Dn + nb + tx * 4;
            float4 o;
            o.x = acc[hm][i][0] + bbv.x; o.y = acc[hm][i][1] + bbv.y;
            o.z = acc[hm][i][2] + bbv.z; o.w = acc[hm][i][3] + bbv.w;
            *(float4*)(Y + rowoff) = o;
        }
}

// ---------------------------------------------------------------------------
// gate_prep: per (chunk m, batch b), thread = r. Elementwise chunk scans:
//   G[τ,r] = Π_{u<=τ} f ;  Ṽ[τ,r] = i·v/G ;  Ñ[τ,r] = Σ i·k/G
// ---------------------------------------------------------------------------
__global__ __launch_bounds__(256) void gate_prep(
    const float* __restrict__ Pf, const float* __restrict__ Pi,
    const float* __restrict__ Pk, const float* __restrict__ Pq,
    float* __restrict__ Gc, float* __restrict__ Vt, float* __restrict__ Nt,
    float* __restrict__ Aend, float* __restrict__ un)
{
    const int m = blockIdx.x;
    const int b = blockIdx.y;
    const int r = threadIdx.x;
    const size_t base = (size_t)b * Sn * Dn + (size_t)m * L * Dn + r;

    float G = 1.0f, Nacc = 0.0f;
    #pragma unroll 4
    for (int t = 0; t < L; ++t) {
        const size_t off = base + (size_t)t * Dn;
        const float f  = Pf[off];
        const float iv = Pi[off];
        const float kv = Pk[off];
        const float vv = Pq[off];     // v = q projection (Wv unused)
        G *= f;
        const float rG = 1.0f / G;
        Gc[off] = G;
        Vt[off] = iv * vv * rG;
        Nacc = fmaf(iv * kv, rG, Nacc);
        Nt[off] = Nacc;
    }
    const size_t s = ((size_t)b * NSEG + m) * Dn + r;
    Aend[s] = G;
    un[s]   = G * Nacc;
}

// ---------------------------------------------------------------------------
// ut_gemm: UT[b,m][c,r] = Aend[r] * Σ_σ K[σ,c]·Ṽ[σ,r]
// ---------------------------------------------------------------------------
__global__ __launch_bounds__(256) void ut_gemm(
    const float* __restrict__ Pk, const float* __restrict__ Vt,
    const float* __restrict__ Aend, float* __restrict__ UT)
{
    __shared__ float As[L][68];   // K^T tile: As[σ][c]
    __shared__ float Bs[L][68];   // Ṽ tile:  Bs[σ][r]

    const int bm   = blockIdx.x;           // b*NSEG + m
    const int tile = blockIdx.y;
    const int cb   = (tile >> 2) * 64;
    const int rb   = (tile & 3) * 64;
    const int b    = bm >> 5;
    const int m    = bm & 31;
    const size_t kb = (size_t)b * Sn * Dn + (size_t)m * L * Dn;
    const int tid = threadIdx.x;

    #pragma unroll
    for (int n = 0; n < 8; ++n) {
        const int e  = n * 256 + tid;
        const int sg = e >> 6;
        const int cc = e & 63;
        As[sg][cc] = Pk[kb + (size_t)sg * Dn + cb + cc];
        Bs[sg][cc] = Vt[kb + (size_t)sg * Dn + rb + cc];
    }
    __syncthreads();

    const int tx = tid & 15;
    const int ty = tid >> 4;
    float acc[4][4];
    #pragma unroll
    for (int i = 0; i < 4; ++i)
        #pragma unroll
        for (int j = 0; j < 4; ++j) acc[i][j] = 0.0f;

    #pragma unroll
    for (int sg = 0; sg < L; ++sg) {
        const float4 a4 = *(const float4*)&As[sg][ty * 4];
        const float4 b4 = *(const float4*)&Bs[sg][tx * 4];
        const float aa[4] = {a4.x, a4.y, a4.z, a4.w};
        const float bb[4] = {b4.x, b4.y, b4.z, b4.w};
        #pragma unroll
        for (int i = 0; i < 4; ++i)
            #pragma unroll
            for (int j = 0; j < 4; ++j)
                acc[i][j] = fmaf(aa[i], bb[j], acc[i][j]);
    }

    const float4 g4 = *(const float4*)(Aend + (size_t)bm * Dn + rb + tx * 4);
    float* ub = UT + (size_t)bm * Dn * Dn;
    #pragma unroll
    for (int i = 0; i < 4; ++i) {
        float4 o;
        o.x = acc[i][0] * g4.x; o.y = acc[i][1] * g4.y;
        o.z = acc[i][2] * g4.z; o.w = acc[i][3] * g4.w;
        *(float4*)(ub + (size_t)(cb + ty * 4 + i) * Dn + rb + tx * 4) = o;
    }
}

// ---------------------------------------------------------------------------
// compose: sequential over chunks (32 steps, elementwise).
// ---------------------------------------------------------------------------
__global__ __launch_bounds__(256) void compose(
    const float* __restrict__ UT, const float* __restrict__ Aend,
    const float* __restrict__ un,
    float* __restrict__ CinT, float* __restrict__ nin)
{
    const int gx = blockIdx.x;
    const int b  = blockIdx.y;
    const int tid = threadIdx.x;

    if (gx == 64) {
        const int r = tid;
        float acc = 0.0f;
        for (int m = 0; m < NSEG; ++m) {
            const size_t s = ((size_t)b * NSEG + m) * Dn + r;
            nin[s] = acc;
            acc = fmaf(Aend[s], acc, un[s]);
        }
        return;
    }

    const int id = gx * 256 + tid;       // 0..16383
    const int c  = id >> 6;
    const int r4 = (id & 63) * 4;

    float4 acc = make_float4(0.f, 0.f, 0.f, 0.f);
    for (int m = 0; m < NSEG; ++m) {
        const size_t bm  = (size_t)b * NSEG + m;
        const size_t idx = bm * Dn * Dn + (size_t)c * Dn + r4;
        *(float4*)(CinT + idx) = acc;
        const float4 a4 = *(const float4*)(Aend + bm * Dn + r4);
        const float4 u4 = *(const float4*)(UT + idx);
        acc.x = fmaf(a4.x, acc.x, u4.x);
        acc.y = fmaf(a4.y, acc.y, u4.y);
        acc.z = fmaf(a4.z, acc.z, u4.z);
        acc.w = fmaf(a4.w, acc.w, u4.w);
    }
}

// ---------------------------------------------------------------------------
// s_gemm: S[b,m][τ,σ] = k_σ·q_τ for σ<=τ else 0.
// ---------------------------------------------------------------------------
__global__ __launch_bounds__(256) void s_gemm(
    const float* __restrict__ Pk, const float* __restrict__ Pq,
    float* __restrict__ Ssm)
{
    const int m = blockIdx.x;
    const int b = blockIdx.y;
    const size_t qb = (size_t)b * Sn * Dn + (size_t)m * L * Dn;
    const int tid = threadIdx.x;
    const int tau = tid >> 3;
    const int s4  = (tid & 7) * 4;

    float a0 = 0.f, a1 = 0.f, a2 = 0.f, a3 = 0.f;
    #pragma unroll 4
    for (int c = 0; c < Dn; c += 4) {
        const float4 q4 = *(const float4*)(Pq + qb + (size_t)tau * Dn + c);
        const float4 k0 = *(const float4*)(Pk + qb + (size_t)(s4 + 0) * Dn + c);
        const float4 k1 = *(const float4*)(Pk + qb + (size_t)(s4 + 1) * Dn + c);
        const float4 k2 = *(const float4*)(Pk + qb + (size_t)(s4 + 2) * Dn + c);
        const float4 k3 = *(const float4*)(Pk + qb + (size_t)(s4 + 3) * Dn + c);
        a0 += q4.x*k0.x + q4.y*k0.y + q4.z*k0.z + q4.w*k0.w;
        a1 += q4.x*k1.x + q4.y*k1.y + q4.z*k1.z + q4.w*k1.w;
        a2 += q4.x*k2.x + q4.y*k2.y + q4.z*k2.z + q4.w*k2.w;
        a3 += q4.x*k3.x + q4.y*k3.y + q4.z*k3.z + q4.w*k3.w;
    }
    float* out = Ssm + ((size_t)b * NSEG + m) * L * L + (size_t)tau * L + s4;
    out[0] = (s4 + 0 <= tau) ? a0 : 0.0f;
    out[1] = (s4 + 1 <= tau) ? a1 : 0.0f;
    out[2] = (s4 + 2 <= tau) ? a2 : 0.0f;
    out[3] = (s4 + 3 <= tau) ? a3 : 0.0f;
}

// ---------------------------------------------------------------------------
// num_gemm: Pnum[τ,r] = G[τ,r]·( Σ_σ S[τ,σ]Ṽ[σ,r] + Σ_c Q[τ,c]CinT[c,r] )
// ---------------------------------------------------------------------------
__global__ __launch_bounds__(256) void num_gemm(
    const float* __restrict__ Pq, const float* __restrict__ Vt,
    const float* __restrict__ Gc, const float* __restrict__ Ssm,
    const float* __restrict__ CinT, float* __restrict__ Pnum)
{
    __shared__ float Sld[L][33];
    __shared__ float Qld[L][257];

    const int rb = blockIdx.x * 128;
    const int m  = blockIdx.y;
    const int b  = blockIdx.z;
    const size_t qb = (size_t)b * Sn * Dn + (size_t)m * L * Dn;
    const size_t ub = ((size_t)b * NSEG + m) * Dn * Dn;
    const size_t sb = ((size_t)b * NSEG + m) * L * L;
    const int tid = threadIdx.x;

    #pragma unroll
    for (int n = 0; n < 4; ++n) {
        const int e = n * 256 + tid;
        Sld[e >> 5][e & 31] = Ssm[sb + e];
    }
    #pragma unroll
    for (int n = 0; n < L; ++n)
        Qld[n][tid] = Pq[qb + (size_t)n * Dn + tid];
    __syncthreads();

    const int tx = tid & 31;
    const int ty = tid >> 5;
    const int r4 = rb + tx * 4;
    const int t4 = ty * 4;

    float4 acc[4];
    #pragma unroll
    for (int i = 0; i < 4; ++i) acc[i] = make_float4(0.f, 0.f, 0.f, 0.f);

    // phase 1: S @ Ṽ  (K = 32)
    #pragma unroll 4
    for (int sg = 0; sg < L; ++sg) {
        const float4 v4 = *(const float4*)(Vt + qb + (size_t)sg * Dn + r4);
        #pragma unroll
        for (int i = 0; i < 4; ++i) {
            const float s = Sld[t4 + i][sg];
            acc[i].x = fmaf(s, v4.x, acc[i].x);
            acc[i].y = fmaf(s, v4.y, acc[i].y);
            acc[i].z = fmaf(s, v4.z, acc[i].z);
            acc[i].w = fmaf(s, v4.w, acc[i].w);
        }
    }

    // phase 2: Q @ Cin^T  (K = 256)
    #pragma unroll 8
    for (int c = 0; c < Dn; ++c) {
        const float4 ct = *(const float4*)(CinT + ub + (size_t)c * Dn + r4);
        #pragma unroll
        for (int i = 0; i < 4; ++i) {
            const float q = Qld[t4 + i][c];
            acc[i].x = fmaf(q, ct.x, acc[i].x);
            acc[i].y = fmaf(q, ct.y, acc[i].y);
            acc[i].z = fmaf(q, ct.z, acc[i].z);
            acc[i].w = fmaf(q, ct.w, acc[i].w);
        }
    }

    #pragma unroll
    for (int i = 0; i < 4; ++i) {
        const size_t off = qb + (size_t)(t4 + i) * Dn + r4;
        const float4 g4 = *(const float4*)(Gc + off);
        float4 o;
        o.x = acc[i].x * g4.x; o.y = acc[i].y * g4.y;
        o.z = acc[i].z * g4.z; o.w = acc[i].w * g4.w;
        *(float4*)(Pnum + off) = o;
    }
}

// ---------------------------------------------------------------------------
// den_kernel: g_den[b,t] = Σ_r q[t,r]·G[t,r]·(nin[m,r] + Ñ[t,r]),  m = t/L.
// ---------------------------------------------------------------------------
__global__ __launch_bounds__(256) void den_kernel(
    const float* __restrict__ Pq, const float* __restrict__ Gc,
    const float* __restrict__ Nt, const float* __restrict__ nin)
{
    const int gx = blockIdx.x;
    const int b  = blockIdx.y;
    const int tid  = threadIdx.x;
    const int lane = tid & 63;
    const int wv   = tid >> 6;
    const int c4   = lane * 4;

    for (int batch = 0; batch < 2; ++batch) {
        const int tbase = gx * 128 + wv * 32 + batch * 16;
        float p[16];
        #pragma unroll
        for (int j = 0; j < 16; ++j) {
            const int t = tbase + j;
            const int m = t >> 5;
            const size_t off = (size_t)b * Sn * Dn + (size_t)t * Dn + c4;
            const float4 q4 = *(const float4*)(Pq + off);
            const float4 g4 = *(const float4*)(Gc + off);
            const float4 n4 = *(const float4*)(Nt + off);
            const float4 i4 = *(const float4*)(nin + ((size_t)b * NSEG + m) * Dn + c4);
            p[j] = q4.x * g4.x * (i4.x + n4.x)
                 + q4.y * g4.y * (i4.y + n4.y)
                 + q4.z * g4.z * (i4.z + n4.z)
                 + q4.w * g4.w * (i4.w + n4.w);
        }
        multi_reduce16(p, lane);
        if ((lane & 3) == 0)
            g_den[b * Sn + tbase + ((lane >> 2) & 15)] = p[0];
    }
}

} // anonymous namespace

extern "C" void kernel_launch(void* const* d_in, const int* in_sizes, int n_in,
                              void* d_out, int out_size, void* d_ws, size_t ws_size,
                              hipStream_t stream)
{
    const float* x  = (const float*)d_in[0];
    const float* Wq = (const float*)d_in[1];  const float* bq = (const float*)d_in[2];
    const float* Wk = (const float*)d_in[3];  const float* bk = (const float*)d_in[4];
    // d_in[5]=Wv, d_in[6]=bv unused (reference uses W_q for v)
    const float* Wf = (const float*)d_in[7];  const float* bf = (const float*)d_in[8];
    const float* Wi = (const float*)d_in[9];  const float* bi = (const float*)d_in[10];
    const float* Wo = (const float*)d_in[11]; const float* bo = (const float*)d_in[12];
    float* out = (float*)d_out;

    float* ws = (float*)d_ws;
    const size_t sz = (size_t)Mn * Dn;            // 2,097,152 floats (8 MB)
    float* Pq = ws;
    float* Pk = ws + sz;
    float* Pf = ws + 2 * sz;
    float* Pi = ws + 3 * sz;
    float* Pn = ws + 4 * sz;                      // numerators
    float* Gc = ws + 5 * sz;                      // G cumprod  [b,t,r]
    float* Vt = ws + 6 * sz;                      // Ṽ          [b,t,r]
    float* Nt = ws + 7 * sz;                      // Ñ cumsum   [b,t,r]
    float* UT   = ws + 8 * sz;                    // [b,m][c][r]  8*sz
    float* CinT = ws + 16 * sz;                   // [b,m][c][r]  8*sz
    float* Ssm  = ws + 24 * sz;                   // [b,m][τ][σ]  262144
    float* Aend = Ssm + (size_t)Bn * NSEG * L * L;
    float* un   = Aend + (size_t)Bn * NSEG * Dn;
    float* nin  = un   + (size_t)Bn * NSEG * Dn;

    proj_gemm<<<dim3(Mn / 128, 8), 256, 0, stream>>>(
        x, Wq, bq, Wk, bk, Wf, bf, Wi, bi, Pq, Pk, Pf, Pi);

    gate_prep<<<dim3(NSEG, Bn), 256, 0, stream>>>(
        Pf, Pi, Pk, Pq, Gc, Vt, Nt, Aend, un);

    ut_gemm<<<dim3(Bn * NSEG, 16), 256, 0, stream>>>(Pk, Vt, Aend, UT);

    compose<<<dim3(65, Bn), 256, 0, stream>>>(UT, Aend, un, CinT, nin);

    s_gemm<<<dim3(NSEG, Bn), 256, 0, stream>>>(Pk, Pq, Ssm);

    num_gemm<<<dim3(2, NSEG, Bn), 256, 0, stream>>>(
        Pq, Vt, Gc, Ssm, CinT, Pn);

    den_kernel<<<dim3(8, Bn), 256, 0, stream>>>(Pq, Gc, Nt, nin);

    out_gemm<<<dim3(Mn / 128, Dn / 64), 256, 0, stream>>>(Pn, Wo, bo, out);
}

// Round 12
// 234.295 us; speedup vs baseline: 1.2250x; 1.0990x over previous
//
#include <hip/hip_runtime.h>
#include <math.h>

namespace {

constexpr int Bn = 8;
constexpr int Sn = 1024;
constexpr int Dn = 256;
constexpr int Mn = Bn * Sn;    // 8192 rows
constexpr int L  = 32;         // chunk length
constexpr int NSEG = Sn / L;   // 32 chunks

typedef __attribute__((ext_vector_type(8))) short short8;   // 8 bf16 (4 VGPRs)
typedef __attribute__((ext_vector_type(4))) float f32x4;    // MFMA acc

__device__ float g_den[Bn * Sn];   // raw n·q per (b,t); clamp applied in out_gemm

__device__ __forceinline__ float sigmoidf_(float x) {
    return 1.0f / (1.0f + __expf(-x));
}

__device__ __forceinline__ unsigned short f2bf(float x) {
    unsigned int u = __float_as_uint(x);
    return (unsigned short)((u + 0x7FFF + ((u >> 16) & 1)) >> 16);   // RNE
}
__device__ __forceinline__ float bf2f(unsigned short h) {
    return __uint_as_float(((unsigned int)h) << 16);
}

// 16-value split butterfly over 64 lanes (HW-validated in r7).
__device__ __forceinline__ void multi_reduce16(float v[16], int lane) {
    {   const bool hi = (lane & 32) != 0;
        #pragma unroll
        for (int i = 0; i < 8; ++i) {
            const float send = hi ? v[i] : v[i + 8];
            const float recv = __shfl_xor(send, 32, 64);
            v[i] = (hi ? v[i + 8] : v[i]) + recv;
        } }
    {   const bool hi = (lane & 16) != 0;
        #pragma unroll
        for (int i = 0; i < 4; ++i) {
            const float send = hi ? v[i] : v[i + 4];
            const float recv = __shfl_xor(send, 16, 64);
            v[i] = (hi ? v[i + 4] : v[i]) + recv;
        } }
    {   const bool hi = (lane & 8) != 0;
        #pragma unroll
        for (int i = 0; i < 2; ++i) {
            const float send = hi ? v[i] : v[i + 2];
            const float recv = __shfl_xor(send, 8, 64);
            v[i] = (hi ? v[i + 2] : v[i]) + recv;
        } }
    {   const bool hi = (lane & 4) != 0;
        const float send = hi ? v[0] : v[1];
        const float recv = __shfl_xor(send, 4, 64);
        v[0] = (hi ? v[1] : v[0]) + recv;
    }
    v[0] += __shfl_xor(v[0], 2, 64);
    v[0] += __shfl_xor(v[0], 1, 64);
}

// ---------------------------------------------------------------------------
// MFMA bf16x3 fused projection GEMM (HW-validated r11). One logical GEMM
// M=8192, N=1024; 128x128 tile, BK=32; hi/lo bf16 split in LDS;
// acc += Ah*Bh + Ah*Bl + Al*Bh  (error ~2^-17, fp32-equivalent).
// ---------------------------------------------------------------------------
__global__ __launch_bounds__(256) void proj_gemm(
    const float* __restrict__ X,
    const float* __restrict__ W0, const float* __restrict__ b0,
    const float* __restrict__ W1, const float* __restrict__ b1,
    const float* __restrict__ W2, const float* __restrict__ b2,
    const float* __restrict__ W3, const float* __restrict__ b3,
    float* __restrict__ Y0, float* __restrict__ Y1,
    float* __restrict__ Y2, float* __restrict__ Y3)
{
    __shared__ unsigned short Ah[128][40];   // 32 k + 8 pad
    __shared__ unsigned short Al[128][40];
    __shared__ unsigned short Bh[128][40];
    __shared__ unsigned short Bl[128][40];   // 40 KB total

    const int tid = threadIdx.x;
    const int mb  = blockIdx.x * 128;
    const int nbg = blockIdx.y;            // 0..7
    const int widx = nbg >> 1;             // which W / activation
    const int ro   = (nbg & 1) * 128;      // row offset inside that W

    const float* Wsel = (widx == 0) ? W0 : (widx == 1) ? W1 : (widx == 2) ? W2 : W3;
    const float* bsel = (widx == 0) ? b0 : (widx == 1) ? b1 : (widx == 2) ? b2 : b3;
    float*       Ysel = (widx == 0) ? Y0 : (widx == 1) ? Y1 : (widx == 2) ? Y2 : Y3;

    const int lane = tid & 63;
    const int wv   = tid >> 6;
    const int wm   = (wv >> 1) * 64;       // wave quadrant
    const int wn   = (wv & 1) * 64;
    const int quad = lane >> 4;
    const int l16  = lane & 15;
    const int srow = tid >> 1;             // staging row 0..127
    const int skq  = (tid & 1) * 16;       // staging k offset 0/16

    f32x4 acc[4][4];
    #pragma unroll
    for (int mt = 0; mt < 4; ++mt)
        #pragma unroll
        for (int nt = 0; nt < 4; ++nt)
            acc[mt][nt] = (f32x4){0.f, 0.f, 0.f, 0.f};

    for (int k0 = 0; k0 < Dn; k0 += 32) {
        float4 xa[4], wb[4];
        #pragma unroll
        for (int c = 0; c < 4; ++c) {
            xa[c] = *(const float4*)(X    + (size_t)(mb + srow) * Dn + k0 + skq + 4 * c);
            wb[c] = *(const float4*)(Wsel + (size_t)(ro + srow) * Dn + k0 + skq + 4 * c);
        }
        __syncthreads();
        #pragma unroll
        for (int c = 0; c < 4; ++c) {
            const float xs[4] = {xa[c].x, xa[c].y, xa[c].z, xa[c].w};
            const float wsv[4] = {wb[c].x, wb[c].y, wb[c].z, wb[c].w};
            ushort4 h, l;
            unsigned short t0;
            t0 = f2bf(xs[0]); h.x = t0; l.x = f2bf(xs[0] - bf2f(t0));
            t0 = f2bf(xs[1]); h.y = t0; l.y = f2bf(xs[1] - bf2f(t0));
            t0 = f2bf(xs[2]); h.z = t0; l.z = f2bf(xs[2] - bf2f(t0));
            t0 = f2bf(xs[3]); h.w = t0; l.w = f2bf(xs[3] - bf2f(t0));
            *(ushort4*)&Ah[srow][skq + 4 * c] = h;
            *(ushort4*)&Al[srow][skq + 4 * c] = l;
            t0 = f2bf(wsv[0]); h.x = t0; l.x = f2bf(wsv[0] - bf2f(t0));
            t0 = f2bf(wsv[1]); h.y = t0; l.y = f2bf(wsv[1] - bf2f(t0));
            t0 = f2bf(wsv[2]); h.z = t0; l.z = f2bf(wsv[2] - bf2f(t0));
            t0 = f2bf(wsv[3]); h.w = t0; l.w = f2bf(wsv[3] - bf2f(t0));
            *(ushort4*)&Bh[srow][skq + 4 * c] = h;
            *(ushort4*)&Bl[srow][skq + 4 * c] = l;
        }
        __syncthreads();

        short8 afh[4], afl[4];
        #pragma unroll
        for (int mt = 0; mt < 4; ++mt) {
            const int row = wm + mt * 16 + l16;
            afh[mt] = *(const short8*)&Ah[row][quad * 8];
            afl[mt] = *(const short8*)&Al[row][quad * 8];
        }
        #pragma unroll
        for (int nt = 0; nt < 4; ++nt) {
            const int row = wn + nt * 16 + l16;
            const short8 bfh = *(const short8*)&Bh[row][quad * 8];
            const short8 bfl = *(const short8*)&Bl[row][quad * 8];
            #pragma unroll
            for (int mt = 0; mt < 4; ++mt) {
                acc[mt][nt] = __builtin_amdgcn_mfma_f32_16x16x32_bf16(
                    afh[mt], bfh, acc[mt][nt], 0, 0, 0);
                acc[mt][nt] = __builtin_amdgcn_mfma_f32_16x16x32_bf16(
                    afh[mt], bfl, acc[mt][nt], 0, 0, 0);
                acc[mt][nt] = __builtin_amdgcn_mfma_f32_16x16x32_bf16(
                    afl[mt], bfh, acc[mt][nt], 0, 0, 0);
            }
        }
    }

    #pragma unroll
    for (int nt = 0; nt < 4; ++nt) {
        const int col = ro + wn + nt * 16 + l16;
        const float bv = bsel[col];
        #pragma unroll
        for (int mt = 0; mt < 4; ++mt) {
            const int rowb = mb + wm + mt * 16 + quad * 4;
            #pragma unroll
            for (int r = 0; r < 4; ++r) {
                float v = acc[mt][nt][r] + bv;
                if (widx == 2)      v = sigmoidf_(v);
                else if (widx == 3) v = __expf(v);
                Ysel[(size_t)(rowb + r) * Dn + col] = v;
            }
        }
    }
}

// ---------------------------------------------------------------------------
// MFMA bf16x3 output GEMM: out = (num * invden) @ Wo^T + bo.
// invd folded into X before hi/lo split. 128x128 tile, grid (64, 2).
// ---------------------------------------------------------------------------
__global__ __launch_bounds__(256) void out_gemm(
    const float* __restrict__ X, const float* __restrict__ W,
    const float* __restrict__ bias, float* __restrict__ Y)
{
    __shared__ unsigned short Ah[128][40];
    __shared__ unsigned short Al[128][40];
    __shared__ unsigned short Bh[128][40];
    __shared__ unsigned short Bl[128][40];

    const int tid = threadIdx.x;
    const int mb  = blockIdx.x * 128;
    const int nb  = blockIdx.y * 128;

    const int lane = tid & 63;
    const int wv   = tid >> 6;
    const int wm   = (wv >> 1) * 64;
    const int wn   = (wv & 1) * 64;
    const int quad = lane >> 4;
    const int l16  = lane & 15;
    const int srow = tid >> 1;
    const int skq  = (tid & 1) * 16;

    const float invd = 1.0f / fmaxf(fabsf(g_den[mb + srow]), 1.0f);

    f32x4 acc[4][4];
    #pragma unroll
    for (int mt = 0; mt < 4; ++mt)
        #pragma unroll
        for (int nt = 0; nt < 4; ++nt)
            acc[mt][nt] = (f32x4){0.f, 0.f, 0.f, 0.f};

    for (int k0 = 0; k0 < Dn; k0 += 32) {
        float4 xa[4], wb[4];
        #pragma unroll
        for (int c = 0; c < 4; ++c) {
            xa[c] = *(const float4*)(X + (size_t)(mb + srow) * Dn + k0 + skq + 4 * c);
            wb[c] = *(const float4*)(W + (size_t)(nb + srow) * Dn + k0 + skq + 4 * c);
            xa[c].x *= invd; xa[c].y *= invd; xa[c].z *= invd; xa[c].w *= invd;
        }
        __syncthreads();
        #pragma unroll
        for (int c = 0; c < 4; ++c) {
            const float xs[4] = {xa[c].x, xa[c].y, xa[c].z, xa[c].w};
            const float wsv[4] = {wb[c].x, wb[c].y, wb[c].z, wb[c].w};
            ushort4 h, l;
            unsigned short t0;
            t0 = f2bf(xs[0]); h.x = t0; l.x = f2bf(xs[0] - bf2f(t0));
            t0 = f2bf(xs[1]); h.y = t0; l.y = f2bf(xs[1] - bf2f(t0));
            t0 = f2bf(xs[2]); h.z = t0; l.z = f2bf(xs[2] - bf2f(t0));
            t0 = f2bf(xs[3]); h.w = t0; l.w = f2bf(xs[3] - bf2f(t0));
            *(ushort4*)&Ah[srow][skq + 4 * c] = h;
            *(ushort4*)&Al[srow][skq + 4 * c] = l;
            t0 = f2bf(wsv[0]); h.x = t0; l.x = f2bf(wsv[0] - bf2f(t0));
            t0 = f2bf(wsv[1]); h.y = t0; l.y = f2bf(wsv[1] - bf2f(t0));
            t0 = f2bf(wsv[2]); h.z = t0; l.z = f2bf(wsv[2] - bf2f(t0));
            t0 = f2bf(wsv[3]); h.w = t0; l.w = f2bf(wsv[3] - bf2f(t0));
            *(ushort4*)&Bh[srow][skq + 4 * c] = h;
            *(ushort4*)&Bl[srow][skq + 4 * c] = l;
        }
        __syncthreads();

        short8 afh[4], afl[4];
        #pragma unroll
        for (int mt = 0; mt < 4; ++mt) {
            const int row = wm + mt * 16 + l16;
            afh[mt] = *(const short8*)&Ah[row][quad * 8];
            afl[mt] = *(const short8*)&Al[row][quad * 8];
        }
        #pragma unroll
        for (int nt = 0; nt < 4; ++nt) {
            const int row = wn + nt * 16 + l16;
            const short8 bfh = *(const short8*)&Bh[row][quad * 8];
            const short8 bfl = *(const short8*)&Bl[row][quad * 8];
            #pragma unroll
            for (int mt = 0; mt < 4; ++mt) {
                acc[mt][nt] = __builtin_amdgcn_mfma_f32_16x16x32_bf16(
                    afh[mt], bfh, acc[mt][nt], 0, 0, 0);
                acc[mt][nt] = __builtin_amdgcn_mfma_f32_16x16x32_bf16(
                    afh[mt], bfl, acc[mt][nt], 0, 0, 0);
                acc[mt][nt] = __builtin_amdgcn_mfma_f32_16x16x32_bf16(
                    afl[mt], bfh, acc[mt][nt], 0, 0, 0);
            }
        }
    }

    #pragma unroll
    for (int nt = 0; nt < 4; ++nt) {
        const int col = nb + wn + nt * 16 + l16;
        const float bv = bias[col];
        #pragma unroll
        for (int mt = 0; mt < 4; ++mt) {
            const int rowb = mb + wm + mt * 16 + quad * 4;
            #pragma unroll
            for (int r = 0; r < 4; ++r) {
                Y[(size_t)(rowb + r) * Dn + col] = acc[mt][nt][r] + bv;
            }
        }
    }
}

// ---------------------------------------------------------------------------
// gate_prep: per (chunk m, batch b), thread = r. Elementwise chunk scans:
//   G[τ,r] = Π_{u<=τ} f ;  Ṽ[τ,r] = i·v/G ;  Ñ[τ,r] = Σ i·k/G
// ---------------------------------------------------------------------------
__global__ __launch_bounds__(256) void gate_prep(
    const float* __restrict__ Pf, const float* __restrict__ Pi,
    const float* __restrict__ Pk, const float* __restrict__ Pq,
    float* __restrict__ Gc, float* __restrict__ Vt, float* __restrict__ Nt,
    float* __restrict__ Aend, float* __restrict__ un)
{
    const int m = blockIdx.x;
    const int b = blockIdx.y;
    const int r = threadIdx.x;
    const size_t base = (size_t)b * Sn * Dn + (size_t)m * L * Dn + r;

    float G = 1.0f, Nacc = 0.0f;
    #pragma unroll 4
    for (int t = 0; t < L; ++t) {
        const size_t off = base + (size_t)t * Dn;
        const float f  = Pf[off];
        const float iv = Pi[off];
        const float kv = Pk[off];
        const float vv = Pq[off];     // v = q projection (Wv unused)
        G *= f;
        const float rG = 1.0f / G;
        Gc[off] = G;
        Vt[off] = iv * vv * rG;
        Nacc = fmaf(iv * kv, rG, Nacc);
        Nt[off] = Nacc;
    }
    const size_t s = ((size_t)b * NSEG + m) * Dn + r;
    Aend[s] = G;
    un[s]   = G * Nacc;
}

// ---------------------------------------------------------------------------
// ut_gemm: UT[b,m][c,r] = Aend[r] * Σ_σ K[σ,c]·Ṽ[σ,r]
// ---------------------------------------------------------------------------
__global__ __launch_bounds__(256) void ut_gemm(
    const float* __restrict__ Pk, const float* __restrict__ Vt,
    const float* __restrict__ Aend, float* __restrict__ UT)
{
    __shared__ float As[L][68];   // K^T tile: As[σ][c]
    __shared__ float Bs[L][68];   // Ṽ tile:  Bs[σ][r]

    const int bm   = blockIdx.x;           // b*NSEG + m
    const int tile = blockIdx.y;
    const int cb   = (tile >> 2) * 64;
    const int rb   = (tile & 3) * 64;
    const int b    = bm >> 5;
    const int m    = bm & 31;
    const size_t kb = (size_t)b * Sn * Dn + (size_t)m * L * Dn;
    const int tid = threadIdx.x;

    #pragma unroll
    for (int n = 0; n < 8; ++n) {
        const int e  = n * 256 + tid;
        const int sg = e >> 6;
        const int cc = e & 63;
        As[sg][cc] = Pk[kb + (size_t)sg * Dn + cb + cc];
        Bs[sg][cc] = Vt[kb + (size_t)sg * Dn + rb + cc];
    }
    __syncthreads();

    const int tx = tid & 15;
    const int ty = tid >> 4;
    float acc[4][4];
    #pragma unroll
    for (int i = 0; i < 4; ++i)
        #pragma unroll
        for (int j = 0; j < 4; ++j) acc[i][j] = 0.0f;

    #pragma unroll
    for (int sg = 0; sg < L; ++sg) {
        const float4 a4 = *(const float4*)&As[sg][ty * 4];
        const float4 b4 = *(const float4*)&Bs[sg][tx * 4];
        const float aa[4] = {a4.x, a4.y, a4.z, a4.w};
        const float bb[4] = {b4.x, b4.y, b4.z, b4.w};
        #pragma unroll
        for (int i = 0; i < 4; ++i)
            #pragma unroll
            for (int j = 0; j < 4; ++j)
                acc[i][j] = fmaf(aa[i], bb[j], acc[i][j]);
    }

    const float4 g4 = *(const float4*)(Aend + (size_t)bm * Dn + rb + tx * 4);
    float* ub = UT + (size_t)bm * Dn * Dn;
    #pragma unroll
    for (int i = 0; i < 4; ++i) {
        float4 o;
        o.x = acc[i][0] * g4.x; o.y = acc[i][1] * g4.y;
        o.z = acc[i][2] * g4.z; o.w = acc[i][3] * g4.w;
        *(float4*)(ub + (size_t)(cb + ty * 4 + i) * Dn + rb + tx * 4) = o;
    }
}

// ---------------------------------------------------------------------------
// compose: sequential over chunks (32 steps, elementwise).
// ---------------------------------------------------------------------------
__global__ __launch_bounds__(256) void compose(
    const float* __restrict__ UT, const float* __restrict__ Aend,
    const float* __restrict__ un,
    float* __restrict__ CinT, float* __restrict__ nin)
{
    const int gx = blockIdx.x;
    const int b  = blockIdx.y;
    const int tid = threadIdx.x;

    if (gx == 64) {
        const int r = tid;
        float acc = 0.0f;
        for (int m = 0; m < NSEG; ++m) {
            const size_t s = ((size_t)b * NSEG + m) * Dn + r;
            nin[s] = acc;
            acc = fmaf(Aend[s], acc, un[s]);
        }
        return;
    }

    const int id = gx * 256 + tid;       // 0..16383
    const int c  = id >> 6;
    const int r4 = (id & 63) * 4;

    float4 acc = make_float4(0.f, 0.f, 0.f, 0.f);
    for (int m = 0; m < NSEG; ++m) {
        const size_t bm  = (size_t)b * NSEG + m;
        const size_t idx = bm * Dn * Dn + (size_t)c * Dn + r4;
        *(float4*)(CinT + idx) = acc;
        const float4 a4 = *(const float4*)(Aend + bm * Dn + r4);
        const float4 u4 = *(const float4*)(UT + idx);
        acc.x = fmaf(a4.x, acc.x, u4.x);
        acc.y = fmaf(a4.y, acc.y, u4.y);
        acc.z = fmaf(a4.z, acc.z, u4.z);
        acc.w = fmaf(a4.w, acc.w, u4.w);
    }
}

// ---------------------------------------------------------------------------
// s_gemm: S[b,m][τ,σ] = k_σ·q_τ for σ<=τ else 0.
// ---------------------------------------------------------------------------
__global__ __launch_bounds__(256) void s_gemm(
    const float* __restrict__ Pk, const float* __restrict__ Pq,
    float* __restrict__ Ssm)
{
    const int m = blockIdx.x;
    const int b = blockIdx.y;
    const size_t qb = (size_t)b * Sn * Dn + (size_t)m * L * Dn;
    const int tid = threadIdx.x;
    const int tau = tid >> 3;
    const int s4  = (tid & 7) * 4;

    float a0 = 0.f, a1 = 0.f, a2 = 0.f, a3 = 0.f;
    #pragma unroll 4
    for (int c = 0; c < Dn; c += 4) {
        const float4 q4 = *(const float4*)(Pq + qb + (size_t)tau * Dn + c);
        const float4 k0 = *(const float4*)(Pk + qb + (size_t)(s4 + 0) * Dn + c);
        const float4 k1 = *(const float4*)(Pk + qb + (size_t)(s4 + 1) * Dn + c);
        const float4 k2 = *(const float4*)(Pk + qb + (size_t)(s4 + 2) * Dn + c);
        const float4 k3 = *(const float4*)(Pk + qb + (size_t)(s4 + 3) * Dn + c);
        a0 += q4.x*k0.x + q4.y*k0.y + q4.z*k0.z + q4.w*k0.w;
        a1 += q4.x*k1.x + q4.y*k1.y + q4.z*k1.z + q4.w*k1.w;
        a2 += q4.x*k2.x + q4.y*k2.y + q4.z*k2.z + q4.w*k2.w;
        a3 += q4.x*k3.x + q4.y*k3.y + q4.z*k3.z + q4.w*k3.w;
    }
    float* out = Ssm + ((size_t)b * NSEG + m) * L * L + (size_t)tau * L + s4;
    out[0] = (s4 + 0 <= tau) ? a0 : 0.0f;
    out[1] = (s4 + 1 <= tau) ? a1 : 0.0f;
    out[2] = (s4 + 2 <= tau) ? a2 : 0.0f;
    out[3] = (s4 + 3 <= tau) ? a3 : 0.0f;
}

// ---------------------------------------------------------------------------
// num_gemm: Pnum[τ,r] = G[τ,r]·( Σ_σ S[τ,σ]Ṽ[σ,r] + Σ_c Q[τ,c]CinT[c,r] )
// ---------------------------------------------------------------------------
__global__ __launch_bounds__(256) void num_gemm(
    const float* __restrict__ Pq, const float* __restrict__ Vt,
    const float* __restrict__ Gc, const float* __restrict__ Ssm,
    const float* __restrict__ CinT, float* __restrict__ Pnum)
{
    __shared__ float Sld[L][33];
    __shared__ float Qld[L][257];

    const int rb = blockIdx.x * 128;
    const int m  = blockIdx.y;
    const int b  = blockIdx.z;
    const size_t qb = (size_t)b * Sn * Dn + (size_t)m * L * Dn;
    const size_t ub = ((size_t)b * NSEG + m) * Dn * Dn;
    const size_t sb = ((size_t)b * NSEG + m) * L * L;
    const int tid = threadIdx.x;

    #pragma unroll
    for (int n = 0; n < 4; ++n) {
        const int e = n * 256 + tid;
        Sld[e >> 5][e & 31] = Ssm[sb + e];
    }
    #pragma unroll
    for (int n = 0; n < L; ++n)
        Qld[n][tid] = Pq[qb + (size_t)n * Dn + tid];
    __syncthreads();

    const int tx = tid & 31;
    const int ty = tid >> 5;
    const int r4 = rb + tx * 4;
    const int t4 = ty * 4;

    float4 acc[4];
    #pragma unroll
    for (int i = 0; i < 4; ++i) acc[i] = make_float4(0.f, 0.f, 0.f, 0.f);

    // phase 1: S @ Ṽ  (K = 32)
    #pragma unroll 4
    for (int sg = 0; sg < L; ++sg) {
        const float4 v4 = *(const float4*)(Vt + qb + (size_t)sg * Dn + r4);
        #pragma unroll
        for (int i = 0; i < 4; ++i) {
            const float s = Sld[t4 + i][sg];
            acc[i].x = fmaf(s, v4.x, acc[i].x);
            acc[i].y = fmaf(s, v4.y, acc[i].y);
            acc[i].z = fmaf(s, v4.z, acc[i].z);
            acc[i].w = fmaf(s, v4.w, acc[i].w);
        }
    }

    // phase 2: Q @ Cin^T  (K = 256)
    #pragma unroll 8
    for (int c = 0; c < Dn; ++c) {
        const float4 ct = *(const float4*)(CinT + ub + (size_t)c * Dn + r4);
        #pragma unroll
        for (int i = 0; i < 4; ++i) {
            const float q = Qld[t4 + i][c];
            acc[i].x = fmaf(q, ct.x, acc[i].x);
            acc[i].y = fmaf(q, ct.y, acc[i].y);
            acc[i].z = fmaf(q, ct.z, acc[i].z);
            acc[i].w = fmaf(q, ct.w, acc[i].w);
        }
    }

    #pragma unroll
    for (int i = 0; i < 4; ++i) {
        const size_t off = qb + (size_t)(t4 + i) * Dn + r4;
        const float4 g4 = *(const float4*)(Gc + off);
        float4 o;
        o.x = acc[i].x * g4.x; o.y = acc[i].y * g4.y;
        o.z = acc[i].z * g4.z; o.w = acc[i].w * g4.w;
        *(float4*)(Pnum + off) = o;
    }
}

// ---------------------------------------------------------------------------
// den_kernel: g_den[b,t] = Σ_r q[t,r]·G[t,r]·(nin[m,r] + Ñ[t,r]),  m = t/L.
// Grid (16, Bn): 64 τ per block, 16 per wave.
// ---------------------------------------------------------------------------
__global__ __launch_bounds__(256) void den_kernel(
    const float* __restrict__ Pq, const float* __restrict__ Gc,
    const float* __restrict__ Nt, const float* __restrict__ nin)
{
    const int gx = blockIdx.x;
    const int b  = blockIdx.y;
    const int tid  = threadIdx.x;
    const int lane = tid & 63;
    const int wv   = tid >> 6;
    const int c4   = lane * 4;

    const int tbase = gx * 64 + wv * 16;
    float p[16];
    #pragma unroll
    for (int j = 0; j < 16; ++j) {
        const int t = tbase + j;
        const int m = t >> 5;
        const size_t off = (size_t)b * Sn * Dn + (size_t)t * Dn + c4;
        const float4 q4 = *(const float4*)(Pq + off);
        const float4 g4 = *(const float4*)(Gc + off);
        const float4 n4 = *(const float4*)(Nt + off);
        const float4 i4 = *(const float4*)(nin + ((size_t)b * NSEG + m) * Dn + c4);
        p[j] = q4.x * g4.x * (i4.x + n4.x)
             + q4.y * g4.y * (i4.y + n4.y)
             + q4.z * g4.z * (i4.z + n4.z)
             + q4.w * g4.w * (i4.w + n4.w);
    }
    multi_reduce16(p, lane);
    if ((lane & 3) == 0)
        g_den[b * Sn + tbase + ((lane >> 2) & 15)] = p[0];
}

} // anonymous namespace

extern "C" void kernel_launch(void* const* d_in, const int* in_sizes, int n_in,
                              void* d_out, int out_size, void* d_ws, size_t ws_size,
                              hipStream_t stream)
{
    const float* x  = (const float*)d_in[0];
    const float* Wq = (const float*)d_in[1];  const float* bq = (const float*)d_in[2];
    const float* Wk = (const float*)d_in[3];  const float* bk = (const float*)d_in[4];
    // d_in[5]=Wv, d_in[6]=bv unused (reference uses W_q for v)
    const float* Wf = (const float*)d_in[7];  const float* bf = (const float*)d_in[8];
    const float* Wi = (const float*)d_in[9];  const float* bi = (const float*)d_in[10];
    const float* Wo = (const float*)d_in[11]; const float* bo = (const float*)d_in[12];
    float* out = (float*)d_out;

    float* ws = (float*)d_ws;
    const size_t sz = (size_t)Mn * Dn;            // 2,097,152 floats (8 MB)
    float* Pq = ws;
    float* Pk = ws + sz;
    float* Pf = ws + 2 * sz;
    float* Pi = ws + 3 * sz;
    float* Pn = ws + 4 * sz;                      // numerators
    float* Gc = ws + 5 * sz;                      // G cumprod  [b,t,r]
    float* Vt = ws + 6 * sz;                      // Ṽ          [b,t,r]
    float* Nt = ws + 7 * sz;                      // Ñ cumsum   [b,t,r]
    float* UT   = ws + 8 * sz;                    // [b,m][c][r]  8*sz
    float* CinT = ws + 16 * sz;                   // [b,m][c][r]  8*sz
    float* Ssm  = ws + 24 * sz;                   // [b,m][τ][σ]  262144
    float* Aend = Ssm + (size_t)Bn * NSEG * L * L;
    float* un   = Aend + (size_t)Bn * NSEG * Dn;
    float* nin  = un   + (size_t)Bn * NSEG * Dn;

    proj_gemm<<<dim3(Mn / 128, 8), 256, 0, stream>>>(
        x, Wq, bq, Wk, bk, Wf, bf, Wi, bi, Pq, Pk, Pf, Pi);

    gate_prep<<<dim3(NSEG, Bn), 256, 0, stream>>>(
        Pf, Pi, Pk, Pq, Gc, Vt, Nt, Aend, un);

    ut_gemm<<<dim3(Bn * NSEG, 16), 256, 0, stream>>>(Pk, Vt, Aend, UT);

    compose<<<dim3(65, Bn), 256, 0, stream>>>(UT, Aend, un, CinT, nin);

    s_gemm<<<dim3(NSEG, Bn), 256, 0, stream>>>(Pk, Pq, Ssm);

    num_gemm<<<dim3(2, NSEG, Bn), 256, 0, stream>>>(
        Pq, Vt, Gc, Ssm, CinT, Pn);

    den_kernel<<<dim3(16, Bn), 256, 0, stream>>>(Pq, Gc, Nt, nin);

    out_gemm<<<dim3(Mn / 128, Dn / 128), 256, 0, stream>>>(Pn, Wo, bo, out);
}

// Round 13
// 231.220 us; speedup vs baseline: 1.2413x; 1.0133x over previous
//
#include <hip/hip_runtime.h>
#include <math.h>

namespace {

constexpr int Bn = 8;
constexpr int Sn = 1024;
constexpr int Dn = 256;
constexpr int Mn = Bn * Sn;    // 8192 rows
constexpr int L  = 32;         // chunk length
constexpr int NSEG = Sn / L;   // 32 chunks

typedef __attribute__((ext_vector_type(8))) short short8;   // 8 bf16 (4 VGPRs)
typedef __attribute__((ext_vector_type(4))) float f32x4;    // MFMA acc

__device__ float g_den[Bn * Sn];   // raw n·q per (b,t); zeroed in prep, built in num

__device__ __forceinline__ float sigmoidf_(float x) {
    return 1.0f / (1.0f + __expf(-x));
}

__device__ __forceinline__ unsigned short f2bf(float x) {
    unsigned int u = __float_as_uint(x);
    return (unsigned short)((u + 0x7FFF + ((u >> 16) & 1)) >> 16);   // RNE
}
__device__ __forceinline__ float bf2f(unsigned short h) {
    return __uint_as_float(((unsigned int)h) << 16);
}

// ---------------------------------------------------------------------------
// MFMA bf16x3 fused projection GEMM (HW-validated r11). One logical GEMM
// M=8192, N=1024; 128x128 tile, BK=32; hi/lo bf16 split in LDS;
// acc += Ah*Bh + Ah*Bl + Al*Bh  (error ~2^-17, fp32-equivalent).
// ---------------------------------------------------------------------------
__global__ __launch_bounds__(256) void proj_gemm(
    const float* __restrict__ X,
    const float* __restrict__ W0, const float* __restrict__ b0,
    const float* __restrict__ W1, const float* __restrict__ b1,
    const float* __restrict__ W2, const float* __restrict__ b2,
    const float* __restrict__ W3, const float* __restrict__ b3,
    float* __restrict__ Y0, float* __restrict__ Y1,
    float* __restrict__ Y2, float* __restrict__ Y3)
{
    __shared__ unsigned short Ah[128][40];   // 32 k + 8 pad
    __shared__ unsigned short Al[128][40];
    __shared__ unsigned short Bh[128][40];
    __shared__ unsigned short Bl[128][40];   // 40 KB total

    const int tid = threadIdx.x;
    const int mb  = blockIdx.x * 128;
    const int nbg = blockIdx.y;            // 0..7
    const int widx = nbg >> 1;             // which W / activation
    const int ro   = (nbg & 1) * 128;      // row offset inside that W

    const float* Wsel = (widx == 0) ? W0 : (widx == 1) ? W1 : (widx == 2) ? W2 : W3;
    const float* bsel = (widx == 0) ? b0 : (widx == 1) ? b1 : (widx == 2) ? b2 : b3;
    float*       Ysel = (widx == 0) ? Y0 : (widx == 1) ? Y1 : (widx == 2) ? Y2 : Y3;

    const int lane = tid & 63;
    const int wv   = tid >> 6;
    const int wm   = (wv >> 1) * 64;       // wave quadrant
    const int wn   = (wv & 1) * 64;
    const int quad = lane >> 4;
    const int l16  = lane & 15;
    const int srow = tid >> 1;             // staging row 0..127
    const int skq  = (tid & 1) * 16;       // staging k offset 0/16

    f32x4 acc[4][4];
    #pragma unroll
    for (int mt = 0; mt < 4; ++mt)
        #pragma unroll
        for (int nt = 0; nt < 4; ++nt)
            acc[mt][nt] = (f32x4){0.f, 0.f, 0.f, 0.f};

    for (int k0 = 0; k0 < Dn; k0 += 32) {
        float4 xa[4], wb[4];
        #pragma unroll
        for (int c = 0; c < 4; ++c) {
            xa[c] = *(const float4*)(X    + (size_t)(mb + srow) * Dn + k0 + skq + 4 * c);
            wb[c] = *(const float4*)(Wsel + (size_t)(ro + srow) * Dn + k0 + skq + 4 * c);
        }
        __syncthreads();
        #pragma unroll
        for (int c = 0; c < 4; ++c) {
            const float xs[4] = {xa[c].x, xa[c].y, xa[c].z, xa[c].w};
            const float wsv[4] = {wb[c].x, wb[c].y, wb[c].z, wb[c].w};
            ushort4 h, l;
            unsigned short t0;
            t0 = f2bf(xs[0]); h.x = t0; l.x = f2bf(xs[0] - bf2f(t0));
            t0 = f2bf(xs[1]); h.y = t0; l.y = f2bf(xs[1] - bf2f(t0));
            t0 = f2bf(xs[2]); h.z = t0; l.z = f2bf(xs[2] - bf2f(t0));
            t0 = f2bf(xs[3]); h.w = t0; l.w = f2bf(xs[3] - bf2f(t0));
            *(ushort4*)&Ah[srow][skq + 4 * c] = h;
            *(ushort4*)&Al[srow][skq + 4 * c] = l;
            t0 = f2bf(wsv[0]); h.x = t0; l.x = f2bf(wsv[0] - bf2f(t0));
            t0 = f2bf(wsv[1]); h.y = t0; l.y = f2bf(wsv[1] - bf2f(t0));
            t0 = f2bf(wsv[2]); h.z = t0; l.z = f2bf(wsv[2] - bf2f(t0));
            t0 = f2bf(wsv[3]); h.w = t0; l.w = f2bf(wsv[3] - bf2f(t0));
            *(ushort4*)&Bh[srow][skq + 4 * c] = h;
            *(ushort4*)&Bl[srow][skq + 4 * c] = l;
        }
        __syncthreads();

        short8 afh[4], afl[4];
        #pragma unroll
        for (int mt = 0; mt < 4; ++mt) {
            const int row = wm + mt * 16 + l16;
            afh[mt] = *(const short8*)&Ah[row][quad * 8];
            afl[mt] = *(const short8*)&Al[row][quad * 8];
        }
        #pragma unroll
        for (int nt = 0; nt < 4; ++nt) {
            const int row = wn + nt * 16 + l16;
            const short8 bfh = *(const short8*)&Bh[row][quad * 8];
            const short8 bfl = *(const short8*)&Bl[row][quad * 8];
            #pragma unroll
            for (int mt = 0; mt < 4; ++mt) {
                acc[mt][nt] = __builtin_amdgcn_mfma_f32_16x16x32_bf16(
                    afh[mt], bfh, acc[mt][nt], 0, 0, 0);
                acc[mt][nt] = __builtin_amdgcn_mfma_f32_16x16x32_bf16(
                    afh[mt], bfl, acc[mt][nt], 0, 0, 0);
                acc[mt][nt] = __builtin_amdgcn_mfma_f32_16x16x32_bf16(
                    afl[mt], bfh, acc[mt][nt], 0, 0, 0);
            }
        }
    }

    #pragma unroll
    for (int nt = 0; nt < 4; ++nt) {
        const int col = ro + wn + nt * 16 + l16;
        const float bv = bsel[col];
        #pragma unroll
        for (int mt = 0; mt < 4; ++mt) {
            const int rowb = mb + wm + mt * 16 + quad * 4;
            #pragma unroll
            for (int r = 0; r < 4; ++r) {
                float v = acc[mt][nt][r] + bv;
                if (widx == 2)      v = sigmoidf_(v);
                else if (widx == 3) v = __expf(v);
                Ysel[(size_t)(rowb + r) * Dn + col] = v;
            }
        }
    }
}

// ---------------------------------------------------------------------------
// MFMA bf16x3 output GEMM: out = (num * invden) @ Wo^T + bo.
// invd folded into X before hi/lo split. 128x128 tile, grid (64, 2).
// ---------------------------------------------------------------------------
__global__ __launch_bounds__(256) void out_gemm(
    const float* __restrict__ X, const float* __restrict__ W,
    const float* __restrict__ bias, float* __restrict__ Y)
{
    __shared__ unsigned short Ah[128][40];
    __shared__ unsigned short Al[128][40];
    __shared__ unsigned short Bh[128][40];
    __shared__ unsigned short Bl[128][40];

    const int tid = threadIdx.x;
    const int mb  = blockIdx.x * 128;
    const int nb  = blockIdx.y * 128;

    const int lane = tid & 63;
    const int wv   = tid >> 6;
    const int wm   = (wv >> 1) * 64;
    const int wn   = (wv & 1) * 64;
    const int quad = lane >> 4;
    const int l16  = lane & 15;
    const int srow = tid >> 1;
    const int skq  = (tid & 1) * 16;

    const float invd = 1.0f / fmaxf(fabsf(g_den[mb + srow]), 1.0f);

    f32x4 acc[4][4];
    #pragma unroll
    for (int mt = 0; mt < 4; ++mt)
        #pragma unroll
        for (int nt = 0; nt < 4; ++nt)
            acc[mt][nt] = (f32x4){0.f, 0.f, 0.f, 0.f};

    for (int k0 = 0; k0 < Dn; k0 += 32) {
        float4 xa[4], wb[4];
        #pragma unroll
        for (int c = 0; c < 4; ++c) {
            xa[c] = *(const float4*)(X + (size_t)(mb + srow) * Dn + k0 + skq + 4 * c);
            wb[c] = *(const float4*)(W + (size_t)(nb + srow) * Dn + k0 + skq + 4 * c);
            xa[c].x *= invd; xa[c].y *= invd; xa[c].z *= invd; xa[c].w *= invd;
        }
        __syncthreads();
        #pragma unroll
        for (int c = 0; c < 4; ++c) {
            const float xs[4] = {xa[c].x, xa[c].y, xa[c].z, xa[c].w};
            const float wsv[4] = {wb[c].x, wb[c].y, wb[c].z, wb[c].w};
            ushort4 h, l;
            unsigned short t0;
            t0 = f2bf(xs[0]); h.x = t0; l.x = f2bf(xs[0] - bf2f(t0));
            t0 = f2bf(xs[1]); h.y = t0; l.y = f2bf(xs[1] - bf2f(t0));
            t0 = f2bf(xs[2]); h.z = t0; l.z = f2bf(xs[2] - bf2f(t0));
            t0 = f2bf(xs[3]); h.w = t0; l.w = f2bf(xs[3] - bf2f(t0));
            *(ushort4*)&Ah[srow][skq + 4 * c] = h;
            *(ushort4*)&Al[srow][skq + 4 * c] = l;
            t0 = f2bf(wsv[0]); h.x = t0; l.x = f2bf(wsv[0] - bf2f(t0));
            t0 = f2bf(wsv[1]); h.y = t0; l.y = f2bf(wsv[1] - bf2f(t0));
            t0 = f2bf(wsv[2]); h.z = t0; l.z = f2bf(wsv[2] - bf2f(t0));
            t0 = f2bf(wsv[3]); h.w = t0; l.w = f2bf(wsv[3] - bf2f(t0));
            *(ushort4*)&Bh[srow][skq + 4 * c] = h;
            *(ushort4*)&Bl[srow][skq + 4 * c] = l;
        }
        __syncthreads();

        short8 afh[4], afl[4];
        #pragma unroll
        for (int mt = 0; mt < 4; ++mt) {
            const int row = wm + mt * 16 + l16;
            afh[mt] = *(const short8*)&Ah[row][quad * 8];
            afl[mt] = *(const short8*)&Al[row][quad * 8];
        }
        #pragma unroll
        for (int nt = 0; nt < 4; ++nt) {
            const int row = wn + nt * 16 + l16;
            const short8 bfh = *(const short8*)&Bh[row][quad * 8];
            const short8 bfl = *(const short8*)&Bl[row][quad * 8];
            #pragma unroll
            for (int mt = 0; mt < 4; ++mt) {
                acc[mt][nt] = __builtin_amdgcn_mfma_f32_16x16x32_bf16(
                    afh[mt], bfh, acc[mt][nt], 0, 0, 0);
                acc[mt][nt] = __builtin_amdgcn_mfma_f32_16x16x32_bf16(
                    afh[mt], bfl, acc[mt][nt], 0, 0, 0);
                acc[mt][nt] = __builtin_amdgcn_mfma_f32_16x16x32_bf16(
                    afl[mt], bfh, acc[mt][nt], 0, 0, 0);
            }
        }
    }

    #pragma unroll
    for (int nt = 0; nt < 4; ++nt) {
        const int col = nb + wn + nt * 16 + l16;
        const float bv = bias[col];
        #pragma unroll
        for (int mt = 0; mt < 4; ++mt) {
            const int rowb = mb + wm + mt * 16 + quad * 4;
            #pragma unroll
            for (int r = 0; r < 4; ++r) {
                Y[(size_t)(rowb + r) * Dn + col] = acc[mt][nt][r] + bv;
            }
        }
    }
}

// ---------------------------------------------------------------------------
// prep: fused gate_prep + s_gemm + g_den zero-init. Grid (NSEG, Bn).
// Phase A (thread = column r): G = Πf, Ṽ = i·v/G, Ñ = Σ i·k/G, Aend, un.
// Phase B (thread = (τ, σ4)): S[τ,σ] = k_σ·q_τ masked σ<=τ  (L2-warm reads).
// ---------------------------------------------------------------------------
__global__ __launch_bounds__(256) void prep(
    const float* __restrict__ Pf, const float* __restrict__ Pi,
    const float* __restrict__ Pk, const float* __restrict__ Pq,
    float* __restrict__ Gc, float* __restrict__ Vt, float* __restrict__ Nt,
    float* __restrict__ Aend, float* __restrict__ un, float* __restrict__ Ssm)
{
    const int m = blockIdx.x;
    const int b = blockIdx.y;
    const int tid = threadIdx.x;

    // zero this chunk's den slots (num_gemm atomically accumulates later)
    if (tid < L) g_den[b * Sn + m * L + tid] = 0.0f;

    // ---- phase A: gate scan, thread = column r ----
    {
        const int r = tid;
        const size_t base = (size_t)b * Sn * Dn + (size_t)m * L * Dn + r;
        float G = 1.0f, Nacc = 0.0f;
        #pragma unroll 4
        for (int t = 0; t < L; ++t) {
            const size_t off = base + (size_t)t * Dn;
            const float f  = Pf[off];
            const float iv = Pi[off];
            const float kv = Pk[off];
            const float vv = Pq[off];     // v = q projection (Wv unused)
            G *= f;
            const float rG = 1.0f / G;
            Gc[off] = G;
            Vt[off] = iv * vv * rG;
            Nacc = fmaf(iv * kv, rG, Nacc);
            Nt[off] = Nacc;
        }
        const size_t s = ((size_t)b * NSEG + m) * Dn + r;
        Aend[s] = G;
        un[s]   = G * Nacc;
    }

    // ---- phase B: S = masked QK^T (no barrier needed; disjoint outputs) ----
    {
        const size_t qb = (size_t)b * Sn * Dn + (size_t)m * L * Dn;
        const int tau = tid >> 3;
        const int s4  = (tid & 7) * 4;

        float a0 = 0.f, a1 = 0.f, a2 = 0.f, a3 = 0.f;
        #pragma unroll 4
        for (int c = 0; c < Dn; c += 4) {
            const float4 q4 = *(const float4*)(Pq + qb + (size_t)tau * Dn + c);
            const float4 k0 = *(const float4*)(Pk + qb + (size_t)(s4 + 0) * Dn + c);
            const float4 k1 = *(const float4*)(Pk + qb + (size_t)(s4 + 1) * Dn + c);
            const float4 k2 = *(const float4*)(Pk + qb + (size_t)(s4 + 2) * Dn + c);
            const float4 k3 = *(const float4*)(Pk + qb + (size_t)(s4 + 3) * Dn + c);
            a0 += q4.x*k0.x + q4.y*k0.y + q4.z*k0.z + q4.w*k0.w;
            a1 += q4.x*k1.x + q4.y*k1.y + q4.z*k1.z + q4.w*k1.w;
            a2 += q4.x*k2.x + q4.y*k2.y + q4.z*k2.z + q4.w*k2.w;
            a3 += q4.x*k3.x + q4.y*k3.y + q4.z*k3.z + q4.w*k3.w;
        }
        float* outp = Ssm + ((size_t)b * NSEG + m) * L * L + (size_t)tau * L + s4;
        outp[0] = (s4 + 0 <= tau) ? a0 : 0.0f;
        outp[1] = (s4 + 1 <= tau) ? a1 : 0.0f;
        outp[2] = (s4 + 2 <= tau) ? a2 : 0.0f;
        outp[3] = (s4 + 3 <= tau) ? a3 : 0.0f;
    }
}

// ---------------------------------------------------------------------------
// ut_gemm: UT[b,m][c,r] = Aend[r] * Σ_σ K[σ,c]·Ṽ[σ,r]
// ---------------------------------------------------------------------------
__global__ __launch_bounds__(256) void ut_gemm(
    const float* __restrict__ Pk, const float* __restrict__ Vt,
    const float* __restrict__ Aend, float* __restrict__ UT)
{
    __shared__ float As[L][68];   // K^T tile: As[σ][c]
    __shared__ float Bs[L][68];   // Ṽ tile:  Bs[σ][r]

    const int bm   = blockIdx.x;           // b*NSEG + m
    const int tile = blockIdx.y;
    const int cb   = (tile >> 2) * 64;
    const int rb   = (tile & 3) * 64;
    const int b    = bm >> 5;
    const int m    = bm & 31;
    const size_t kb = (size_t)b * Sn * Dn + (size_t)m * L * Dn;
    const int tid = threadIdx.x;

    #pragma unroll
    for (int n = 0; n < 8; ++n) {
        const int e  = n * 256 + tid;
        const int sg = e >> 6;
        const int cc = e & 63;
        As[sg][cc] = Pk[kb + (size_t)sg * Dn + cb + cc];
        Bs[sg][cc] = Vt[kb + (size_t)sg * Dn + rb + cc];
    }
    __syncthreads();

    const int tx = tid & 15;
    const int ty = tid >> 4;
    float acc[4][4];
    #pragma unroll
    for (int i = 0; i < 4; ++i)
        #pragma unroll
        for (int j = 0; j < 4; ++j) acc[i][j] = 0.0f;

    #pragma unroll
    for (int sg = 0; sg < L; ++sg) {
        const float4 a4 = *(const float4*)&As[sg][ty * 4];
        const float4 b4 = *(const float4*)&Bs[sg][tx * 4];
        const float aa[4] = {a4.x, a4.y, a4.z, a4.w};
        const float bb[4] = {b4.x, b4.y, b4.z, b4.w};
        #pragma unroll
        for (int i = 0; i < 4; ++i)
            #pragma unroll
            for (int j = 0; j < 4; ++j)
                acc[i][j] = fmaf(aa[i], bb[j], acc[i][j]);
    }

    const float4 g4 = *(const float4*)(Aend + (size_t)bm * Dn + rb + tx * 4);
    float* ub = UT + (size_t)bm * Dn * Dn;
    #pragma unroll
    for (int i = 0; i < 4; ++i) {
        float4 o;
        o.x = acc[i][0] * g4.x; o.y = acc[i][1] * g4.y;
        o.z = acc[i][2] * g4.z; o.w = acc[i][3] * g4.w;
        *(float4*)(ub + (size_t)(cb + ty * 4 + i) * Dn + rb + tx * 4) = o;
    }
}

// ---------------------------------------------------------------------------
// compose: sequential over chunks (32 steps, elementwise).
// ---------------------------------------------------------------------------
__global__ __launch_bounds__(256) void compose(
    const float* __restrict__ UT, const float* __restrict__ Aend,
    const float* __restrict__ un,
    float* __restrict__ CinT, float* __restrict__ nin)
{
    const int gx = blockIdx.x;
    const int b  = blockIdx.y;
    const int tid = threadIdx.x;

    if (gx == 64) {
        const int r = tid;
        float acc = 0.0f;
        for (int m = 0; m < NSEG; ++m) {
            const size_t s = ((size_t)b * NSEG + m) * Dn + r;
            nin[s] = acc;
            acc = fmaf(Aend[s], acc, un[s]);
        }
        return;
    }

    const int id = gx * 256 + tid;       // 0..16383
    const int c  = id >> 6;
    const int r4 = (id & 63) * 4;

    float4 acc = make_float4(0.f, 0.f, 0.f, 0.f);
    for (int m = 0; m < NSEG; ++m) {
        const size_t bm  = (size_t)b * NSEG + m;
        const size_t idx = bm * Dn * Dn + (size_t)c * Dn + r4;
        *(float4*)(CinT + idx) = acc;
        const float4 a4 = *(const float4*)(Aend + bm * Dn + r4);
        const float4 u4 = *(const float4*)(UT + idx);
        acc.x = fmaf(a4.x, acc.x, u4.x);
        acc.y = fmaf(a4.y, acc.y, u4.y);
        acc.z = fmaf(a4.z, acc.z, u4.z);
        acc.w = fmaf(a4.w, acc.w, u4.w);
    }
}

// ---------------------------------------------------------------------------
// num_gemm: Pnum[τ,r] = G[τ,r]·( Σ_σ S[τ,σ]Ṽ[σ,r] + Σ_c Q[τ,c]CinT[c,r] )
// Epilogue also accumulates this block's r-half partial of the denominator
// den[b,t] = Σ_r q·G·(nin+Ñ) via 32-lane butterfly + atomicAdd (den_kernel
// fused away; g_den zeroed in prep).
// ---------------------------------------------------------------------------
__global__ __launch_bounds__(256) void num_gemm(
    const float* __restrict__ Pq, const float* __restrict__ Vt,
    const float* __restrict__ Gc, const float* __restrict__ Ssm,
    const float* __restrict__ CinT, const float* __restrict__ Nt,
    const float* __restrict__ nin, float* __restrict__ Pnum)
{
    __shared__ float Sld[L][33];
    __shared__ float Qld[L][257];

    const int rb = blockIdx.x * 128;
    const int m  = blockIdx.y;
    const int b  = blockIdx.z;
    const size_t qb = (size_t)b * Sn * Dn + (size_t)m * L * Dn;
    const size_t ub = ((size_t)b * NSEG + m) * Dn * Dn;
    const size_t sb = ((size_t)b * NSEG + m) * L * L;
    const int tid = threadIdx.x;

    #pragma unroll
    for (int n = 0; n < 4; ++n) {
        const int e = n * 256 + tid;
        Sld[e >> 5][e & 31] = Ssm[sb + e];
    }
    #pragma unroll
    for (int n = 0; n < L; ++n)
        Qld[n][tid] = Pq[qb + (size_t)n * Dn + tid];
    __syncthreads();

    const int tx = tid & 31;
    const int ty = tid >> 5;
    const int r4 = rb + tx * 4;
    const int t4 = ty * 4;

    float4 acc[4];
    #pragma unroll
    for (int i = 0; i < 4; ++i) acc[i] = make_float4(0.f, 0.f, 0.f, 0.f);

    // phase 1: S @ Ṽ  (K = 32)
    #pragma unroll 4
    for (int sg = 0; sg < L; ++sg) {
        const float4 v4 = *(const float4*)(Vt + qb + (size_t)sg * Dn + r4);
        #pragma unroll
        for (int i = 0; i < 4; ++i) {
            const float s = Sld[t4 + i][sg];
            acc[i].x = fmaf(s, v4.x, acc[i].x);
            acc[i].y = fmaf(s, v4.y, acc[i].y);
            acc[i].z = fmaf(s, v4.z, acc[i].z);
            acc[i].w = fmaf(s, v4.w, acc[i].w);
        }
    }

    // phase 2: Q @ Cin^T  (K = 256)
    #pragma unroll 8
    for (int c = 0; c < Dn; ++c) {
        const float4 ct = *(const float4*)(CinT + ub + (size_t)c * Dn + r4);
        #pragma unroll
        for (int i = 0; i < 4; ++i) {
            const float q = Qld[t4 + i][c];
            acc[i].x = fmaf(q, ct.x, acc[i].x);
            acc[i].y = fmaf(q, ct.y, acc[i].y);
            acc[i].z = fmaf(q, ct.z, acc[i].z);
            acc[i].w = fmaf(q, ct.w, acc[i].w);
        }
    }

    // epilogue: write numerators + accumulate denominator partials
    const float4 i4 = *(const float4*)(nin + ((size_t)b * NSEG + m) * Dn + r4);
    float dp[4];
    #pragma unroll
    for (int i = 0; i < 4; ++i) {
        const size_t off = qb + (size_t)(t4 + i) * Dn + r4;
        const float4 g4 = *(const float4*)(Gc + off);
        const float4 q4 = *(const float4*)(Pq + off);
        const float4 n4 = *(const float4*)(Nt + off);
        float4 o;
        o.x = acc[i].x * g4.x; o.y = acc[i].y * g4.y;
        o.z = acc[i].z * g4.z; o.w = acc[i].w * g4.w;
        *(float4*)(Pnum + off) = o;
        dp[i] = q4.x * g4.x * (i4.x + n4.x)
              + q4.y * g4.y * (i4.y + n4.y)
              + q4.z * g4.z * (i4.z + n4.z)
              + q4.w * g4.w * (i4.w + n4.w);
    }

    // butterfly over tx (lanes with same ty are a contiguous 32-lane half)
    #pragma unroll
    for (int s = 1; s < 32; s <<= 1) {
        #pragma unroll
        for (int i = 0; i < 4; ++i)
            dp[i] += __shfl_xor(dp[i], s, 64);
    }
    if (tx == 0) {
        #pragma unroll
        for (int i = 0; i < 4; ++i)
            atomicAdd(&g_den[b * Sn + m * L + t4 + i], dp[i]);
    }
}

} // anonymous namespace

extern "C" void kernel_launch(void* const* d_in, const int* in_sizes, int n_in,
                              void* d_out, int out_size, void* d_ws, size_t ws_size,
                              hipStream_t stream)
{
    const float* x  = (const float*)d_in[0];
    const float* Wq = (const float*)d_in[1];  const float* bq = (const float*)d_in[2];
    const float* Wk = (const float*)d_in[3];  const float* bk = (const float*)d_in[4];
    // d_in[5]=Wv, d_in[6]=bv unused (reference uses W_q for v)
    const float* Wf = (const float*)d_in[7];  const float* bf = (const float*)d_in[8];
    const float* Wi = (const float*)d_in[9];  const float* bi = (const float*)d_in[10];
    const float* Wo = (const float*)d_in[11]; const float* bo = (const float*)d_in[12];
    float* out = (float*)d_out;

    float* ws = (float*)d_ws;
    const size_t sz = (size_t)Mn * Dn;            // 2,097,152 floats (8 MB)
    float* Pq = ws;
    float* Pk = ws + sz;
    float* Pf = ws + 2 * sz;
    float* Pi = ws + 3 * sz;
    float* Pn = ws + 4 * sz;                      // numerators
    float* Gc = ws + 5 * sz;                      // G cumprod  [b,t,r]
    float* Vt = ws + 6 * sz;                      // Ṽ          [b,t,r]
    float* Nt = ws + 7 * sz;                      // Ñ cumsum   [b,t,r]
    float* UT   = ws + 8 * sz;                    // [b,m][c][r]  8*sz
    float* CinT = ws + 16 * sz;                   // [b,m][c][r]  8*sz
    float* Ssm  = ws + 24 * sz;                   // [b,m][τ][σ]  262144
    float* Aend = Ssm + (size_t)Bn * NSEG * L * L;
    float* un   = Aend + (size_t)Bn * NSEG * Dn;
    float* nin  = un   + (size_t)Bn * NSEG * Dn;

    proj_gemm<<<dim3(Mn / 128, 8), 256, 0, stream>>>(
        x, Wq, bq, Wk, bk, Wf, bf, Wi, bi, Pq, Pk, Pf, Pi);

    prep<<<dim3(NSEG, Bn), 256, 0, stream>>>(
        Pf, Pi, Pk, Pq, Gc, Vt, Nt, Aend, un, Ssm);

    ut_gemm<<<dim3(Bn * NSEG, 16), 256, 0, stream>>>(Pk, Vt, Aend, UT);

    compose<<<dim3(65, Bn), 256, 0, stream>>>(UT, Aend, un, CinT, nin);

    num_gemm<<<dim3(2, NSEG, Bn), 256, 0, stream>>>(
        Pq, Vt, Gc, Ssm, CinT, Nt, nin, Pn);

    out_gemm<<<dim3(Mn / 128, Dn / 128), 256, 0, stream>>>(Pn, Wo, bo, out);
}